// Round 2
// baseline (1652.158 us; speedup 1.0000x reference)
//
#include <hip/hip_runtime.h>
#include <hip/hip_bf16.h>
#include <math.h>

#define LRELU_SLOPE 0.2f
typedef __hip_bfloat16 bf16;
typedef __hip_bfloat162 bf16x2;

typedef short s8v __attribute__((ext_vector_type(8)));   // 8 bf16 (4 VGPRs)
typedef float f4v __attribute__((ext_vector_type(4)));   // MFMA acc

__device__ __forceinline__ float lrelu(float v) { return v > 0.f ? v : LRELU_SLOPE * v; }
__device__ __forceinline__ float b2f(short b) {
  return __uint_as_float(((unsigned)(unsigned short)b) << 16);
}

__device__ __forceinline__ void st2(float* p, float x, float y) {
  *(float2*)p = float2{x, y};
}

// nontemporal 16B store: streaming output shouldn't evict the h gather set
template <typename T>
__device__ __forceinline__ void nt_store16(void* p, T v) {
  union { T t; unsigned long long q[2]; } u;
  u.t = v;
  __builtin_nontemporal_store(u.q[0], (unsigned long long*)p);
  __builtin_nontemporal_store(u.q[1], (unsigned long long*)p + 1);
}

// ---------------- zero helper (avoid hipMemsetAsync in capture) ----------------

__global__ void k_zero(unsigned int* __restrict__ p, long n) {
  long i = (long)blockIdx.x * blockDim.x + threadIdx.x;
  if (i < n) p[i] = 0u;
}

__global__ void k_zero_out(float* __restrict__ out, int n) {
  int i = blockIdx.x * blockDim.x + threadIdx.x;
  if (i < n) out[i] = 0.f;
}

// ---------------- dtype prep: x -> bf16, W -> bf16 transposed ----------------

__global__ void k_cvt(const float* __restrict__ x, bf16* __restrict__ xb, long n) {
  long i = (long)blockIdx.x * blockDim.x + threadIdx.x;
  if (i < n) xb[i] = __float2bfloat16(x[i]);
}

// W[K][NN] (f32) -> Wt[NN][K] (bf16)
__global__ void k_tw(const float* __restrict__ W, bf16* __restrict__ Wt, int K, int NN) {
  int i = blockIdx.x * blockDim.x + threadIdx.x;
  if (i >= K * NN) return;
  int k = i / NN, n = i - k * NN;
  Wt[(size_t)n * K + k] = __float2bfloat16(W[i]);
}

// ---------------- preprocessing: counting-sort edges by dst ----------------

__global__ void k_hist(const int* __restrict__ dst, int* __restrict__ deg, int E, int Et) {
  int e = blockIdx.x * blockDim.x + threadIdx.x;
  if (e >= Et) return;
  int d = (e < E) ? dst[e] : (e - E);   // self-loops appended
  atomicAdd(&deg[d], 1);
}

__global__ void k_hist1(const int* __restrict__ idx, int* __restrict__ deg, int n) {
  int i = blockIdx.x * blockDim.x + threadIdx.x;
  if (i < n) atomicAdd(&deg[idx[i]], 1);
}

__global__ void k_scan1(const int* __restrict__ deg, int* __restrict__ offs,
                        int* __restrict__ bsum, int n) {
  __shared__ int sd[256];
  int t = threadIdx.x;
  int base = blockIdx.x * 1024 + t * 4;
  int v[4]; int tsum = 0;
#pragma unroll
  for (int i = 0; i < 4; ++i) { v[i] = (base + i < n) ? deg[base + i] : 0; tsum += v[i]; }
  sd[t] = tsum;
  __syncthreads();
  for (int off = 1; off < 256; off <<= 1) {
    int x = (t >= off) ? sd[t - off] : 0;
    __syncthreads();
    sd[t] += x;
    __syncthreads();
  }
  int excl = sd[t] - tsum;
#pragma unroll
  for (int i = 0; i < 4; ++i) { if (base + i < n) offs[base + i] = excl; excl += v[i]; }
  if (t == 255) bsum[blockIdx.x] = sd[255];
}

__global__ void k_scan2(int* bsum, int nb) {
  if (threadIdx.x == 0 && blockIdx.x == 0) {
    int run = 0;
    for (int i = 0; i < nb; ++i) { int t = bsum[i]; bsum[i] = run; run += t; }
  }
}

__global__ void k_scan3(int* __restrict__ offs, const int* __restrict__ bsum, int n, int total) {
  int t = threadIdx.x;
  int base = blockIdx.x * 1024 + t * 4;
  int add = bsum[blockIdx.x];
#pragma unroll
  for (int i = 0; i < 4; ++i) if (base + i < n) offs[base + i] += add;
  if (blockIdx.x == 0 && t == 0) offs[n] = total;
}

__global__ void k_scatter(const int* __restrict__ src, const int* __restrict__ dst,
                          const int* __restrict__ offs, int* __restrict__ cur,
                          int* __restrict__ ssrc, int E, int Et) {
  int e = blockIdx.x * blockDim.x + threadIdx.x;
  if (e >= Et) return;
  int s, d;
  if (e < E) { s = src[e]; d = dst[e]; } else { s = d = e - E; }
  int pos = offs[d] + atomicAdd(&cur[d], 1);
  ssrc[pos] = s;
}

// ---------------- bf16 MFMA GEMM: C[M,NN](bf16) = A[M,K](bf16) @ Wt[NN,K](bf16)^T ----
// One block owns a full 64-row x NN panel: A tile staged ONCE per kb and reused
// across all NB_T bn-tiles (cuts A HBM traffic by NB_T vs the old (M/64, NN/64)
// grid). afrag hoisted out of the bn loop (8 s8v live). acc[NB_T][4] ~ 96 VGPR
// for NB_T=6 -> ~3 waves/SIMD, m97-like occupancy.

template <int NB_T>
__global__ __launch_bounds__(256) void k_gemm_mfma(const bf16* __restrict__ A,
                                                   const bf16* __restrict__ Wt,
                                                   bf16* __restrict__ C, int K) {
  constexpr int NN = NB_T * 64;
  __shared__ __align__(16) short sA[64 * 64];   // 8 KB, 64 rows x 64 cols bf16
  int t = threadIdx.x;
  int wv = t >> 6, lane = t & 63;
  int quad = lane >> 4, l15 = lane & 15;
  size_t bm0 = (size_t)blockIdx.x * 64;
  const bf16* Ab = A + bm0 * K;
  f4v acc[NB_T][4];
#pragma unroll
  for (int bn = 0; bn < NB_T; ++bn)
#pragma unroll
    for (int ms = 0; ms < 4; ++ms) acc[bn][ms] = f4v{0, 0, 0, 0};

  for (int kb = 0; kb < K; kb += 64) {
#pragma unroll
    for (int j = 0; j < 2; ++j) {
      int idx = j * 256 + t;
      int row = idx >> 3, p = idx & 7;
      int c = p ^ (row & 7);                  // global 16B-chunk landing at pos p
      const bf16* g = Ab + (size_t)row * K + kb + c * 8;
      __builtin_amdgcn_global_load_lds(
          (const __attribute__((address_space(1))) void*)g,
          (__attribute__((address_space(3))) void*)((char*)sA + (size_t)(j * 256 + wv * 64) * 16),
          16, 0, 0);
    }
    __syncthreads();
    s8v af[2][4];
#pragma unroll
    for (int kk = 0; kk < 2; ++kk)
#pragma unroll
      for (int ms = 0; ms < 4; ++ms) {
        int row = ms * 16 + l15;
        int pos = (kk * 4 + quad) ^ (row & 7);
        af[kk][ms] = *(const s8v*)((const char*)sA + (size_t)row * 128 + pos * 16);
      }
#pragma unroll
    for (int bn = 0; bn < NB_T; ++bn) {
      const bf16* Bp = Wt + (size_t)(bn * 64 + wv * 16 + l15) * K + kb;
#pragma unroll
      for (int kk = 0; kk < 2; ++kk) {
        s8v bfrag = *(const s8v*)(Bp + kk * 32 + quad * 8);
#pragma unroll
        for (int ms = 0; ms < 4; ++ms)
          acc[bn][ms] = __builtin_amdgcn_mfma_f32_16x16x32_bf16(af[kk][ms], bfrag, acc[bn][ms], 0, 0, 0);
      }
    }
    __syncthreads();
  }
  // C/D layout: col = lane&15, row = quad*4 + reg  [m89/m91 verified]
#pragma unroll
  for (int bn = 0; bn < NB_T; ++bn) {
    int coln = bn * 64 + wv * 16 + l15;
#pragma unroll
    for (int ms = 0; ms < 4; ++ms)
#pragma unroll
      for (int r = 0; r < 4; ++r)
        C[(bm0 + ms * 16 + quad * 4 + r) * NN + coln] = __float2bfloat16(acc[bn][ms][r]);
  }
}

// ---------------- attention logits: one wave per node, 16 lanes per head ----------------
// al_s/al_d stored PADDED to 4 floats per node (H=3) so per-edge alpha gathers
// in k_agg_h are single dword gathers at [node*4+hd].

template <int H>
__global__ void k_al(const bf16* __restrict__ h, const float* __restrict__ as,
                     const float* __restrict__ ad, float* __restrict__ al_s,
                     float* __restrict__ al_d, int N) {
  constexpr int SP = (H > 1) ? 4 : 1;
  int n = (blockIdx.x * blockDim.x + threadIdx.x) >> 6;
  int lane = threadIdx.x & 63;
  if (n >= N) return;
  int hd = lane >> 4;
  bool active = (hd < H);
  int hdc = active ? hd : 0;
  int f8 = (lane & 15) * 8;
  const bf16* hp = h + (size_t)n * (H * 128) + hdc * 128 + f8;
  s8v hv = *(const s8v*)hp;
  float ss = 0.f, sd = 0.f;
#pragma unroll
  for (int i = 0; i < 8; ++i) {
    float v = b2f(hv[i]);
    ss += v * as[hdc * 128 + f8 + i];
    sd += v * ad[hdc * 128 + f8 + i];
  }
#pragma unroll
  for (int off = 8; off; off >>= 1) {
    ss += __shfl_xor(ss, off, 64);
    sd += __shfl_xor(sd, off, 64);
  }
  if (active && (lane & 15) == 0) {
    al_s[n * SP + hd] = ss;
    al_d[n * SP + hd] = sd;
  }
}

// -------- fused segment-softmax + weighted aggregation, PER-HEAD --------
// One wave per node, one head (128 channels) per dispatch. Sequential per-head
// dispatches keep the active 51 MB head slab L3-resident (vs 154 MB x 2 buffers
// thrashing the 256 MB L3 when all heads were fused). Gather: 4 lane-groups of
// 16 handle 4 edges per instruction (16 lanes x 16B = one 256B head row), full
// 64-lane utilization. Alpha values redistributed to groups via __shfl (no LDS
// stash). Online softmax (exact for deg<=64; rescale branch covers the rest).

template <int SP, int RS, int OS, typename OT>
__global__ __launch_bounds__(256) void k_agg_h(const bf16* __restrict__ hbuf,  // +hd*128
                          const int* __restrict__ ssrc, const int* __restrict__ offs,
                          const float* __restrict__ al_s, const float* __restrict__ al_d,
                          int hd, const float* __restrict__ bias,               // +hd*128
                          OT* __restrict__ out,                                 // +hd*128
                          int N) {
  int n = (blockIdx.x * blockDim.x + threadIdx.x) >> 6;
  int lane = threadIdx.x & 63;
  if (n >= N) return;
  int start = offs[n], end = offs[n + 1];
  float ald = al_d[(size_t)n * SP + hd];
  int g = lane >> 4, l15 = lane & 15;

  float m = -1e30f, den = 0.f;
  float acc[8];
#pragma unroll
  for (int i = 0; i < 8; ++i) acc[i] = 0.f;

  for (int cb = start; cb < end; cb += 64) {
    int cl = end - cb; if (cl > 64) cl = 64;
    bool el = lane < cl;
    int mys = el ? ssrc[cb + lane] : 0;
    float ev = el ? lrelu(al_s[(size_t)mys * SP + hd] + ald) : -1e30f;

    // chunk max (wave-uniform after the tree)
    float v = ev;
#pragma unroll
    for (int off = 32; off; off >>= 1) v = fmaxf(v, __shfl_xor(v, off, 64));
    float nm = fmaxf(v, m);
    if (cb > start) {                    // online rescale; wave-uniform branch
      float sc = __expf(m - nm);
      den *= sc;
#pragma unroll
      for (int i = 0; i < 8; ++i) acc[i] *= sc;
    }
    m = nm;
    float myex = el ? __expf(ev - m) : 0.f;

    // 16 edges per iteration: 4 sub-steps x 4 edges-in-flight
    for (int r = 0; r < cl; r += 16) {
      int su[4]; float a[4];
#pragma unroll
      for (int j = 0; j < 4; ++j) {
        int srcl = r + j * 4 + g;        // lanes >= cl hold myex=0 -> contribute 0
        su[j] = __shfl(mys, srcl, 64);
        a[j] = __shfl(myex, srcl, 64);
      }
      s8v hv[4];
#pragma unroll
      for (int j = 0; j < 4; ++j)
        hv[j] = *(const s8v*)(hbuf + (size_t)su[j] * RS + l15 * 8);
#pragma unroll
      for (int j = 0; j < 4; ++j) {
#pragma unroll
        for (int i = 0; i < 8; ++i) acc[i] += a[j] * b2f(hv[j][i]);
        den += a[j];
      }
    }
  }

  // reduce across the 4 edge-groups (xor over lane bits 4,5)
#pragma unroll
  for (int off = 16; off <= 32; off <<= 1) {
    den += __shfl_xor(den, off, 64);
#pragma unroll
    for (int i = 0; i < 8; ++i) acc[i] += __shfl_xor(acc[i], off, 64);
  }

  float rr = 1.f / (den + 1e-16f);
  if constexpr (sizeof(OT) == 2) {
    if (lane < 16) {                     // 16 lanes x 16B = contiguous 256B row
      s8v ov;
#pragma unroll
      for (int i = 0; i < 8; ++i) {
        float o = lrelu(acc[i] * rr + bias[l15 * 8 + i]);
        bf16 b = __float2bfloat16(o);
        ov[i] = *(short*)&b;
      }
      nt_store16((OT*)out + (size_t)n * OS + l15 * 8, ov);
    }
  } else {
    if (lane < 32) {                     // lanes 0-15: ch +0..3, 16-31: ch +4..7
      float4 ov;
#pragma unroll
      for (int i = 0; i < 4; ++i)
        (&ov.x)[i] = lrelu(acc[g * 4 + i] * rr + bias[l15 * 8 + g * 4 + i]);
      nt_store16((OT*)out + (size_t)n * OS + l15 * 8 + g * 4, ov);
    }
  }
}

// ---------------- global mean pool: one wave per graph, no atomics ----------------

__global__ void k_pool(const float* __restrict__ h, const int* __restrict__ goffs,
                       float* __restrict__ out, int G) {
  int g = (blockIdx.x * blockDim.x + threadIdx.x) >> 6;
  int lane = threadIdx.x & 63;
  if (g >= G) return;
  int s = goffs[g], e = goffs[g + 1];
  float ax = 0.f, ay = 0.f;
  for (int n = s; n < e; ++n) {
    float2 v = *(const float2*)&h[(size_t)n * 128 + lane * 2];
    ax += v.x; ay += v.y;
  }
  float c = fmaxf((float)(e - s), 1.f);
  st2(&out[(size_t)g * 128 + lane * 2], ax / c, ay / c);
}

// ---------------- host launcher ----------------

extern "C" void kernel_launch(void* const* d_in, const int* in_sizes, int n_in,
                              void* d_out, int out_size, void* d_ws, size_t ws_size,
                              hipStream_t stream) {
  const float* x   = (const float*)d_in[0];
  const int*   ei  = (const int*)d_in[1];
  const int*   bat = (const int*)d_in[2];
  const float* W1  = (const float*)d_in[3];
  const float* a1s = (const float*)d_in[4];
  const float* a1d = (const float*)d_in[5];
  const float* b1  = (const float*)d_in[6];
  const float* W2  = (const float*)d_in[7];
  const float* a2s = (const float*)d_in[8];
  const float* a2d = (const float*)d_in[9];
  const float* b2  = (const float*)d_in[10];
  const float* W3  = (const float*)d_in[11];
  const float* a3s = (const float*)d_in[12];
  const float* a3d = (const float*)d_in[13];
  const float* b3  = (const float*)d_in[14];
  float* out = (float*)d_out;

  const int N = in_sizes[2];          // 200000
  const int E = in_sizes[1] / 2;      // 1600000
  const int Et = E + N;               // with self-loops
  const int G = out_size / 128;       // 5000

  // ---- workspace carve (bf16 intermediates) ----
  char* p = (char*)d_ws;
  auto carve = [&](size_t bytes) { void* r = (void*)p; p += (bytes + 255) & ~(size_t)255; return r; };
  bf16*  bufA   = (bf16*)carve((size_t)N * 384 * 2);   // agg out / GEMM A; also hosts xb & fp32 layer-3 out
  bf16*  bufB   = (bf16*)carve((size_t)N * 384 * 2);   // GEMM output h
  float* al_s   = (float*)carve((size_t)N * 4 * 4);    // padded to 4 floats/node
  float* al_d   = (float*)carve((size_t)N * 4 * 4);
  int*   ssrc   = (int*)carve((size_t)Et * 4);
  int*   offs   = (int*)carve((size_t)(N + 1) * 4);
  int*   deg    = (int*)carve((size_t)N * 4);
  int*   cur    = (int*)carve((size_t)N * 4);
  int*   bsum   = (int*)carve(4096 * 4);
  int*   gdeg   = (int*)carve((size_t)G * 4);
  int*   goffs  = (int*)carve((size_t)(G + 1) * 4);
  bf16*  Wt1    = (bf16*)carve((size_t)384 * 128 * 2);
  bf16*  Wt2    = (bf16*)carve((size_t)384 * 384 * 2);
  bf16*  Wt3    = (bf16*)carve((size_t)128 * 384 * 2);
  size_t need = (size_t)(p - (char*)d_ws);

  if (ws_size < need) {
    k_zero_out<<<(out_size + 255) / 256, 256, 0, stream>>>(out, out_size);
    return;
  }

  const int* esrc = ei;
  const int* edst = ei + E;

  int ebl = (Et + 255) / 256;
  int NB = (N + 1023) / 1024;
  int GB = (G + 1023) / 1024;
  int nodeWaveBlocks = (N * 64 + 255) / 256;
  int gemmBlocks = (N + 63) / 64;

  // ---- prep: weight transpose+cast, x cast (xb aliases bufA) ----
  bf16* xb = bufA;
  k_cvt<<<((long)N * 128 + 255) / 256, 256, 0, stream>>>(x, xb, (long)N * 128);
  k_tw<<<(128 * 384 + 255) / 256, 256, 0, stream>>>(W1, Wt1, 128, 384);
  k_tw<<<(384 * 384 + 255) / 256, 256, 0, stream>>>(W2, Wt2, 384, 384);
  k_tw<<<(384 * 128 + 255) / 256, 256, 0, stream>>>(W3, Wt3, 384, 128);

  // ---- sort edges by dst ----
  k_zero<<<(N + 255) / 256, 256, 0, stream>>>((unsigned int*)deg, N);
  k_hist<<<ebl, 256, 0, stream>>>(edst, deg, E, Et);
  k_scan1<<<NB, 256, 0, stream>>>(deg, offs, bsum, N);
  k_scan2<<<1, 64, 0, stream>>>(bsum, NB);
  k_scan3<<<NB, 256, 0, stream>>>(offs, bsum, N, Et);
  k_zero<<<(N + 255) / 256, 256, 0, stream>>>((unsigned int*)cur, N);
  k_scatter<<<ebl, 256, 0, stream>>>(esrc, edst, offs, cur, ssrc, E, Et);

  // ---- graph offsets for pool (batch is sorted) ----
  k_zero<<<(G + 255) / 256, 256, 0, stream>>>((unsigned int*)gdeg, G);
  k_hist1<<<(N + 255) / 256, 256, 0, stream>>>(bat, gdeg, N);
  k_scan1<<<GB, 256, 0, stream>>>(gdeg, goffs, bsum, G);
  k_scan2<<<1, 64, 0, stream>>>(bsum, GB);
  k_scan3<<<GB, 256, 0, stream>>>(goffs, bsum, G, N);

  // ---- layer 1: xb[N,128] @ W1 -> bufB[N,384] ----
  k_gemm_mfma<6><<<gemmBlocks, 256, 0, stream>>>(xb, Wt1, bufB, 128);
  k_al<3><<<nodeWaveBlocks, 256, 0, stream>>>(bufB, a1s, a1d, al_s, al_d, N);
  for (int hd = 0; hd < 3; ++hd)
    k_agg_h<4, 384, 384, bf16><<<nodeWaveBlocks, 256, 0, stream>>>(
        bufB + hd * 128, ssrc, offs, al_s, al_d, hd, b1 + hd * 128, bufA + hd * 128, N);

  // ---- layer 2: bufA[N,384] @ W2 -> bufB[N,384] ----
  k_gemm_mfma<6><<<gemmBlocks, 256, 0, stream>>>(bufA, Wt2, bufB, 384);
  k_al<3><<<nodeWaveBlocks, 256, 0, stream>>>(bufB, a2s, a2d, al_s, al_d, N);
  for (int hd = 0; hd < 3; ++hd)
    k_agg_h<4, 384, 384, bf16><<<nodeWaveBlocks, 256, 0, stream>>>(
        bufB + hd * 128, ssrc, offs, al_s, al_d, hd, b2 + hd * 128, bufA + hd * 128, N);

  // ---- layer 3: bufA[N,384] @ W3 -> bufB[N,128], heads=1, fp32 agg out ----
  k_gemm_mfma<2><<<gemmBlocks, 256, 0, stream>>>(bufA, Wt3, bufB, 384);
  k_al<1><<<nodeWaveBlocks, 256, 0, stream>>>(bufB, a3s, a3d, al_s, al_d, N);
  float* out3 = (float*)bufA;
  k_agg_h<1, 128, 128, float><<<nodeWaveBlocks, 256, 0, stream>>>(
      bufB, ssrc, offs, al_s, al_d, 0, b3, out3, N);

  // ---- global mean pool: segmented, atomic-free ----
  k_pool<<<(G * 64 + 255) / 256, 256, 0, stream>>>(out3, goffs, out, G);
}

// Round 3
// 1631.349 us; speedup vs baseline: 1.0128x; 1.0128x over previous
//
#include <hip/hip_runtime.h>
#include <hip/hip_bf16.h>
#include <math.h>

#define LRELU_SLOPE 0.2f
typedef __hip_bfloat16 bf16;
typedef __hip_bfloat162 bf16x2;

typedef short s8v __attribute__((ext_vector_type(8)));   // 8 bf16 (4 VGPRs)
typedef float f4v __attribute__((ext_vector_type(4)));   // MFMA acc

__device__ __forceinline__ float lrelu(float v) { return v > 0.f ? v : LRELU_SLOPE * v; }
__device__ __forceinline__ float b2f(short b) {
  return __uint_as_float(((unsigned)(unsigned short)b) << 16);
}

__device__ __forceinline__ void st2(float* p, float x, float y) {
  *(float2*)p = float2{x, y};
}

// nontemporal 16B store: streaming output shouldn't evict the h gather set
template <typename T>
__device__ __forceinline__ void nt_store16(void* p, T v) {
  union { T t; unsigned long long q[2]; } u;
  u.t = v;
  __builtin_nontemporal_store(u.q[0], (unsigned long long*)p);
  __builtin_nontemporal_store(u.q[1], (unsigned long long*)p + 1);
}

// ---------------- zero helper (avoid hipMemsetAsync in capture) ----------------

__global__ void k_zero(unsigned int* __restrict__ p, long n) {
  long i = (long)blockIdx.x * blockDim.x + threadIdx.x;
  if (i < n) p[i] = 0u;
}

__global__ void k_zero_out(float* __restrict__ out, int n) {
  int i = blockIdx.x * blockDim.x + threadIdx.x;
  if (i < n) out[i] = 0.f;
}

// ---------------- dtype prep: x -> bf16, W -> bf16 transposed ----------------

__global__ void k_cvt(const float* __restrict__ x, bf16* __restrict__ xb, long n) {
  long i = (long)blockIdx.x * blockDim.x + threadIdx.x;
  if (i < n) xb[i] = __float2bfloat16(x[i]);
}

// W[K][NN] (f32) -> Wt[NN][K] (bf16)
__global__ void k_tw(const float* __restrict__ W, bf16* __restrict__ Wt, int K, int NN) {
  int i = blockIdx.x * blockDim.x + threadIdx.x;
  if (i >= K * NN) return;
  int k = i / NN, n = i - k * NN;
  Wt[(size_t)n * K + k] = __float2bfloat16(W[i]);
}

// ---------------- preprocessing: counting-sort edges by dst ----------------

__global__ void k_hist(const int* __restrict__ dst, int* __restrict__ deg, int E, int Et) {
  int e = blockIdx.x * blockDim.x + threadIdx.x;
  if (e >= Et) return;
  int d = (e < E) ? dst[e] : (e - E);   // self-loops appended
  atomicAdd(&deg[d], 1);
}

__global__ void k_hist1(const int* __restrict__ idx, int* __restrict__ deg, int n) {
  int i = blockIdx.x * blockDim.x + threadIdx.x;
  if (i < n) atomicAdd(&deg[idx[i]], 1);
}

__global__ void k_scan1(const int* __restrict__ deg, int* __restrict__ offs,
                        int* __restrict__ bsum, int n) {
  __shared__ int sd[256];
  int t = threadIdx.x;
  int base = blockIdx.x * 1024 + t * 4;
  int v[4]; int tsum = 0;
#pragma unroll
  for (int i = 0; i < 4; ++i) { v[i] = (base + i < n) ? deg[base + i] : 0; tsum += v[i]; }
  sd[t] = tsum;
  __syncthreads();
  for (int off = 1; off < 256; off <<= 1) {
    int x = (t >= off) ? sd[t - off] : 0;
    __syncthreads();
    sd[t] += x;
    __syncthreads();
  }
  int excl = sd[t] - tsum;
#pragma unroll
  for (int i = 0; i < 4; ++i) { if (base + i < n) offs[base + i] = excl; excl += v[i]; }
  if (t == 255) bsum[blockIdx.x] = sd[255];
}

__global__ void k_scan2(int* bsum, int nb) {
  if (threadIdx.x == 0 && blockIdx.x == 0) {
    int run = 0;
    for (int i = 0; i < nb; ++i) { int t = bsum[i]; bsum[i] = run; run += t; }
  }
}

__global__ void k_scan3(int* __restrict__ offs, const int* __restrict__ bsum, int n, int total) {
  int t = threadIdx.x;
  int base = blockIdx.x * 1024 + t * 4;
  int add = bsum[blockIdx.x];
#pragma unroll
  for (int i = 0; i < 4; ++i) if (base + i < n) offs[base + i] += add;
  if (blockIdx.x == 0 && t == 0) offs[n] = total;
}

__global__ void k_scatter(const int* __restrict__ src, const int* __restrict__ dst,
                          const int* __restrict__ offs, int* __restrict__ cur,
                          int* __restrict__ ssrc, int E, int Et) {
  int e = blockIdx.x * blockDim.x + threadIdx.x;
  if (e >= Et) return;
  int s, d;
  if (e < E) { s = src[e]; d = dst[e]; } else { s = d = e - E; }
  int pos = offs[d] + atomicAdd(&cur[d], 1);
  ssrc[pos] = s;
}

// ---------------- bf16 MFMA GEMM: C[M,NN](bf16) = A[M,K](bf16) @ Wt[NN,K](bf16)^T ----
// 8-wave panel kernel: one block owns a 64-row x NN panel (A staged ONCE ->
// minimal A traffic), wave-group g in {0,1} owns half the bn-tiles so per-wave
// acc is only NB_T/2*16 VGPR (round-2's acc[6][4]=96 VGPR capped occupancy at
// ~2 waves/SIMD -> latency-bound, MfmaUtil 12.5%). Double-buffered LDS with
// stage-issued-first (T3 minimum 2-phase): next K-tile's global_load_lds is in
// flight across the whole compute phase; one __syncthreads per K-step.

template <int NB_T>
__global__ __launch_bounds__(512) void k_gemm8(const bf16* __restrict__ A,
                                               const bf16* __restrict__ Wt,
                                               bf16* __restrict__ C, int K) {
  constexpr int NN = NB_T * 64;
  constexpr int NBW = NB_T / 2;             // bn tiles per wave-group
  __shared__ __align__(16) short sA[2][64 * 64];   // 2 x 8 KB
  int t = threadIdx.x;
  int wv = t >> 6, lane = t & 63;
  int grp = wv >> 2;                        // bn half
  int wcg = wv & 3;                         // 16-col slice within a bn tile
  int quad = lane >> 4, l15 = lane & 15;
  size_t bm0 = (size_t)blockIdx.x * 64;
  const bf16* Ab = A + bm0 * K;

  // staging map (identical swizzle to the verified round-0 kernel; idx == t)
  int srow = t >> 3, sp = t & 7;
  int sc = sp ^ (srow & 7);                 // global 16B-chunk landing at pos sp
  const bf16* gbase = Ab + (size_t)srow * K + sc * 8;
  char* ldst0 = (char*)sA[0] + (size_t)(wv * 64) * 16;   // wave-uniform base
  char* ldst1 = (char*)sA[1] + (size_t)(wv * 64) * 16;

  f4v acc[NBW][4];
#pragma unroll
  for (int bn = 0; bn < NBW; ++bn)
#pragma unroll
    for (int ms = 0; ms < 4; ++ms) acc[bn][ms] = f4v{0, 0, 0, 0};

  int nk = K >> 6;
  // prologue: stage tile 0 into buf 0
  __builtin_amdgcn_global_load_lds(
      (const __attribute__((address_space(1))) void*)gbase,
      (__attribute__((address_space(3))) void*)ldst0, 16, 0, 0);
  __syncthreads();

  for (int ik = 0; ik < nk; ++ik) {
    int cur = ik & 1;
    // issue next tile's stage FIRST (overlaps with compute below)
    if (ik + 1 < nk)
      __builtin_amdgcn_global_load_lds(
          (const __attribute__((address_space(1))) void*)(gbase + (ik + 1) * 64),
          (__attribute__((address_space(3))) void*)(cur ? ldst0 : ldst1), 16, 0, 0);

    const char* sb = (const char*)sA[cur];
    s8v af[2][4];
#pragma unroll
    for (int kk = 0; kk < 2; ++kk)
#pragma unroll
      for (int ms = 0; ms < 4; ++ms) {
        int row = ms * 16 + l15;
        int pos = (kk * 4 + quad) ^ (row & 7);
        af[kk][ms] = *(const s8v*)(sb + (size_t)row * 128 + pos * 16);
      }
#pragma unroll
    for (int bn = 0; bn < NBW; ++bn) {
      const bf16* Bp = Wt + (size_t)((grp * NBW + bn) * 64 + wcg * 16 + l15) * K + ik * 64;
#pragma unroll
      for (int kk = 0; kk < 2; ++kk) {
        s8v bfrag = *(const s8v*)(Bp + kk * 32 + quad * 8);
#pragma unroll
        for (int ms = 0; ms < 4; ++ms)
          acc[bn][ms] = __builtin_amdgcn_mfma_f32_16x16x32_bf16(af[kk][ms], bfrag, acc[bn][ms], 0, 0, 0);
      }
    }
    __syncthreads();   // drains vmcnt (next tile landed) + guards buffer reuse
  }
  // C/D layout: col = lane&15, row = quad*4 + reg  [m89/m91 verified]
#pragma unroll
  for (int bn = 0; bn < NBW; ++bn) {
    int coln = (grp * NBW + bn) * 64 + wcg * 16 + l15;
#pragma unroll
    for (int ms = 0; ms < 4; ++ms)
#pragma unroll
      for (int r = 0; r < 4; ++r)
        C[(bm0 + ms * 16 + quad * 4 + r) * NN + coln] = __float2bfloat16(acc[bn][ms][r]);
  }
}

// ---------------- attention logits: one wave per node, 16 lanes per head ----------------
// al_s/al_d stored PADDED to 4 floats per node (H=3) so per-edge alpha gathers
// in k_agg_h are single dword gathers at [node*4+hd].

template <int H>
__global__ void k_al(const bf16* __restrict__ h, const float* __restrict__ as,
                     const float* __restrict__ ad, float* __restrict__ al_s,
                     float* __restrict__ al_d, int N) {
  constexpr int SP = (H > 1) ? 4 : 1;
  int n = (blockIdx.x * blockDim.x + threadIdx.x) >> 6;
  int lane = threadIdx.x & 63;
  if (n >= N) return;
  int hd = lane >> 4;
  bool active = (hd < H);
  int hdc = active ? hd : 0;
  int f8 = (lane & 15) * 8;
  const bf16* hp = h + (size_t)n * (H * 128) + hdc * 128 + f8;
  s8v hv = *(const s8v*)hp;
  float ss = 0.f, sd = 0.f;
#pragma unroll
  for (int i = 0; i < 8; ++i) {
    float v = b2f(hv[i]);
    ss += v * as[hdc * 128 + f8 + i];
    sd += v * ad[hdc * 128 + f8 + i];
  }
#pragma unroll
  for (int off = 8; off; off >>= 1) {
    ss += __shfl_xor(ss, off, 64);
    sd += __shfl_xor(sd, off, 64);
  }
  if (active && (lane & 15) == 0) {
    al_s[n * SP + hd] = ss;
    al_d[n * SP + hd] = sd;
  }
}

// -------- fused segment-softmax + weighted aggregation, PER-HEAD --------
// One wave per node, one head (128 channels) per dispatch. Sequential per-head
// dispatches keep the active 51 MB head slab L3-resident. Gather: 4 lane-groups
// of 16 handle 4 edges per instruction (16 lanes x 16B = one 256B head row).
// Alpha values redistributed to groups via __shfl. Online softmax (exact for
// deg<=64; rescale branch covers the rest).

template <int SP, int RS, int OS, typename OT>
__global__ __launch_bounds__(256) void k_agg_h(const bf16* __restrict__ hbuf,  // +hd*128
                          const int* __restrict__ ssrc, const int* __restrict__ offs,
                          const float* __restrict__ al_s, const float* __restrict__ al_d,
                          int hd, const float* __restrict__ bias,               // +hd*128
                          OT* __restrict__ out,                                 // +hd*128
                          int N) {
  int n = (blockIdx.x * blockDim.x + threadIdx.x) >> 6;
  int lane = threadIdx.x & 63;
  if (n >= N) return;
  int start = offs[n], end = offs[n + 1];
  float ald = al_d[(size_t)n * SP + hd];
  int g = lane >> 4, l15 = lane & 15;

  float m = -1e30f, den = 0.f;
  float acc[8];
#pragma unroll
  for (int i = 0; i < 8; ++i) acc[i] = 0.f;

  for (int cb = start; cb < end; cb += 64) {
    int cl = end - cb; if (cl > 64) cl = 64;
    bool el = lane < cl;
    int mys = el ? ssrc[cb + lane] : 0;
    float ev = el ? lrelu(al_s[(size_t)mys * SP + hd] + ald) : -1e30f;

    // chunk max (wave-uniform after the tree)
    float v = ev;
#pragma unroll
    for (int off = 32; off; off >>= 1) v = fmaxf(v, __shfl_xor(v, off, 64));
    float nm = fmaxf(v, m);
    if (cb > start) {                    // online rescale; wave-uniform branch
      float sc = __expf(m - nm);
      den *= sc;
#pragma unroll
      for (int i = 0; i < 8; ++i) acc[i] *= sc;
    }
    m = nm;
    float myex = el ? __expf(ev - m) : 0.f;

    // 16 edges per iteration: 4 sub-steps x 4 edges-in-flight
    for (int r = 0; r < cl; r += 16) {
      int su[4]; float a[4];
#pragma unroll
      for (int j = 0; j < 4; ++j) {
        int srcl = r + j * 4 + g;        // lanes >= cl hold myex=0 -> contribute 0
        su[j] = __shfl(mys, srcl, 64);
        a[j] = __shfl(myex, srcl, 64);
      }
      s8v hv[4];
#pragma unroll
      for (int j = 0; j < 4; ++j)
        hv[j] = *(const s8v*)(hbuf + (size_t)su[j] * RS + l15 * 8);
#pragma unroll
      for (int j = 0; j < 4; ++j) {
#pragma unroll
        for (int i = 0; i < 8; ++i) acc[i] += a[j] * b2f(hv[j][i]);
        den += a[j];
      }
    }
  }

  // reduce across the 4 edge-groups (xor over lane bits 4,5)
#pragma unroll
  for (int off = 16; off <= 32; off <<= 1) {
    den += __shfl_xor(den, off, 64);
#pragma unroll
    for (int i = 0; i < 8; ++i) acc[i] += __shfl_xor(acc[i], off, 64);
  }

  float rr = 1.f / (den + 1e-16f);
  if constexpr (sizeof(OT) == 2) {
    if (lane < 16) {                     // 16 lanes x 16B = contiguous 256B row
      s8v ov;
#pragma unroll
      for (int i = 0; i < 8; ++i) {
        float o = lrelu(acc[i] * rr + bias[l15 * 8 + i]);
        bf16 b = __float2bfloat16(o);
        ov[i] = *(short*)&b;
      }
      nt_store16((OT*)out + (size_t)n * OS + l15 * 8, ov);
    }
  } else {
    if (lane < 32) {                     // lanes 0-15: ch +0..3, 16-31: ch +4..7
      float4 ov;
#pragma unroll
      for (int i = 0; i < 4; ++i)
        (&ov.x)[i] = lrelu(acc[g * 4 + i] * rr + bias[l15 * 8 + g * 4 + i]);
      nt_store16((OT*)out + (size_t)n * OS + l15 * 8 + g * 4, ov);
    }
  }
}

// ---------------- global mean pool: one wave per graph, no atomics ----------------

__global__ void k_pool(const float* __restrict__ h, const int* __restrict__ goffs,
                       float* __restrict__ out, int G) {
  int g = (blockIdx.x * blockDim.x + threadIdx.x) >> 6;
  int lane = threadIdx.x & 63;
  if (g >= G) return;
  int s = goffs[g], e = goffs[g + 1];
  float ax = 0.f, ay = 0.f;
  for (int n = s; n < e; ++n) {
    float2 v = *(const float2*)&h[(size_t)n * 128 + lane * 2];
    ax += v.x; ay += v.y;
  }
  float c = fmaxf((float)(e - s), 1.f);
  st2(&out[(size_t)g * 128 + lane * 2], ax / c, ay / c);
}

// ---------------- host launcher ----------------

extern "C" void kernel_launch(void* const* d_in, const int* in_sizes, int n_in,
                              void* d_out, int out_size, void* d_ws, size_t ws_size,
                              hipStream_t stream) {
  const float* x   = (const float*)d_in[0];
  const int*   ei  = (const int*)d_in[1];
  const int*   bat = (const int*)d_in[2];
  const float* W1  = (const float*)d_in[3];
  const float* a1s = (const float*)d_in[4];
  const float* a1d = (const float*)d_in[5];
  const float* b1  = (const float*)d_in[6];
  const float* W2  = (const float*)d_in[7];
  const float* a2s = (const float*)d_in[8];
  const float* a2d = (const float*)d_in[9];
  const float* b2  = (const float*)d_in[10];
  const float* W3  = (const float*)d_in[11];
  const float* a3s = (const float*)d_in[12];
  const float* a3d = (const float*)d_in[13];
  const float* b3  = (const float*)d_in[14];
  float* out = (float*)d_out;

  const int N = in_sizes[2];          // 200000
  const int E = in_sizes[1] / 2;      // 1600000
  const int Et = E + N;               // with self-loops
  const int G = out_size / 128;       // 5000

  // ---- workspace carve (bf16 intermediates) ----
  char* p = (char*)d_ws;
  auto carve = [&](size_t bytes) { void* r = (void*)p; p += (bytes + 255) & ~(size_t)255; return r; };
  bf16*  bufA   = (bf16*)carve((size_t)N * 384 * 2);   // agg out / GEMM A; also hosts xb & fp32 layer-3 out
  bf16*  bufB   = (bf16*)carve((size_t)N * 384 * 2);   // GEMM output h
  float* al_s   = (float*)carve((size_t)N * 4 * 4);    // padded to 4 floats/node
  float* al_d   = (float*)carve((size_t)N * 4 * 4);
  int*   ssrc   = (int*)carve((size_t)Et * 4);
  int*   offs   = (int*)carve((size_t)(N + 1) * 4);
  int*   deg    = (int*)carve((size_t)N * 4);
  int*   cur    = (int*)carve((size_t)N * 4);
  int*   bsum   = (int*)carve(4096 * 4);
  int*   gdeg   = (int*)carve((size_t)G * 4);
  int*   goffs  = (int*)carve((size_t)(G + 1) * 4);
  bf16*  Wt1    = (bf16*)carve((size_t)384 * 128 * 2);
  bf16*  Wt2    = (bf16*)carve((size_t)384 * 384 * 2);
  bf16*  Wt3    = (bf16*)carve((size_t)128 * 384 * 2);
  size_t need = (size_t)(p - (char*)d_ws);

  if (ws_size < need) {
    k_zero_out<<<(out_size + 255) / 256, 256, 0, stream>>>(out, out_size);
    return;
  }

  const int* esrc = ei;
  const int* edst = ei + E;

  int ebl = (Et + 255) / 256;
  int NB = (N + 1023) / 1024;
  int GB = (G + 1023) / 1024;
  int nodeWaveBlocks = (N * 64 + 255) / 256;
  int gemmBlocks = (N + 63) / 64;

  // ---- prep: weight transpose+cast, x cast (xb aliases bufA) ----
  bf16* xb = bufA;
  k_cvt<<<((long)N * 128 + 255) / 256, 256, 0, stream>>>(x, xb, (long)N * 128);
  k_tw<<<(128 * 384 + 255) / 256, 256, 0, stream>>>(W1, Wt1, 128, 384);
  k_tw<<<(384 * 384 + 255) / 256, 256, 0, stream>>>(W2, Wt2, 384, 384);
  k_tw<<<(384 * 128 + 255) / 256, 256, 0, stream>>>(W3, Wt3, 384, 128);

  // ---- sort edges by dst ----
  k_zero<<<(N + 255) / 256, 256, 0, stream>>>((unsigned int*)deg, N);
  k_hist<<<ebl, 256, 0, stream>>>(edst, deg, E, Et);
  k_scan1<<<NB, 256, 0, stream>>>(deg, offs, bsum, N);
  k_scan2<<<1, 64, 0, stream>>>(bsum, NB);
  k_scan3<<<NB, 256, 0, stream>>>(offs, bsum, N, Et);
  k_zero<<<(N + 255) / 256, 256, 0, stream>>>((unsigned int*)cur, N);
  k_scatter<<<ebl, 256, 0, stream>>>(esrc, edst, offs, cur, ssrc, E, Et);

  // ---- graph offsets for pool (batch is sorted) ----
  k_zero<<<(G + 255) / 256, 256, 0, stream>>>((unsigned int*)gdeg, G);
  k_hist1<<<(N + 255) / 256, 256, 0, stream>>>(bat, gdeg, N);
  k_scan1<<<GB, 256, 0, stream>>>(gdeg, goffs, bsum, G);
  k_scan2<<<1, 64, 0, stream>>>(bsum, GB);
  k_scan3<<<GB, 256, 0, stream>>>(goffs, bsum, G, N);

  // ---- layer 1: xb[N,128] @ W1 -> bufB[N,384] ----
  k_gemm8<6><<<gemmBlocks, 512, 0, stream>>>(xb, Wt1, bufB, 128);
  k_al<3><<<nodeWaveBlocks, 256, 0, stream>>>(bufB, a1s, a1d, al_s, al_d, N);
  for (int hd = 0; hd < 3; ++hd)
    k_agg_h<4, 384, 384, bf16><<<nodeWaveBlocks, 256, 0, stream>>>(
        bufB + hd * 128, ssrc, offs, al_s, al_d, hd, b1 + hd * 128, bufA + hd * 128, N);

  // ---- layer 2: bufA[N,384] @ W2 -> bufB[N,384] ----
  k_gemm8<6><<<gemmBlocks, 512, 0, stream>>>(bufA, Wt2, bufB, 384);
  k_al<3><<<nodeWaveBlocks, 256, 0, stream>>>(bufB, a2s, a2d, al_s, al_d, N);
  for (int hd = 0; hd < 3; ++hd)
    k_agg_h<4, 384, 384, bf16><<<nodeWaveBlocks, 256, 0, stream>>>(
        bufB + hd * 128, ssrc, offs, al_s, al_d, hd, b2 + hd * 128, bufA + hd * 128, N);

  // ---- layer 3: bufA[N,384] @ W3 -> bufB[N,128], heads=1, fp32 agg out ----
  k_gemm8<2><<<gemmBlocks, 512, 0, stream>>>(bufA, Wt3, bufB, 384);
  k_al<1><<<nodeWaveBlocks, 256, 0, stream>>>(bufB, a3s, a3d, al_s, al_d, N);
  float* out3 = (float*)bufA;
  k_agg_h<1, 128, 128, float><<<nodeWaveBlocks, 256, 0, stream>>>(
      bufB, ssrc, offs, al_s, al_d, 0, b3, out3, N);

  // ---- global mean pool: segmented, atomic-free ----
  k_pool<<<(G * 64 + 255) / 256, 256, 0, stream>>>(out3, goffs, out, G);
}

// Round 4
// 1511.359 us; speedup vs baseline: 1.0932x; 1.0794x over previous
//
#include <hip/hip_runtime.h>
#include <hip/hip_bf16.h>
#include <math.h>

#define LRELU_SLOPE 0.2f
typedef __hip_bfloat16 bf16;
typedef __hip_bfloat162 bf16x2;

typedef short s8v __attribute__((ext_vector_type(8)));   // 8 bf16 (4 VGPRs)
typedef short s4v __attribute__((ext_vector_type(4)));   // 4 bf16 (2 VGPRs)
typedef float f4v __attribute__((ext_vector_type(4)));   // MFMA acc

__device__ __forceinline__ float lrelu(float v) { return v > 0.f ? v : LRELU_SLOPE * v; }
__device__ __forceinline__ float b2f(short b) {
  return __uint_as_float(((unsigned)(unsigned short)b) << 16);
}

__device__ __forceinline__ void st2(float* p, float x, float y) {
  *(float2*)p = float2{x, y};
}

// nontemporal 16B store: streaming output shouldn't evict the h gather set
template <typename T>
__device__ __forceinline__ void nt_store16(void* p, T v) {
  union { T t; unsigned long long q[2]; } u;
  u.t = v;
  __builtin_nontemporal_store(u.q[0], (unsigned long long*)p);
  __builtin_nontemporal_store(u.q[1], (unsigned long long*)p + 1);
}

// ---------------- zero helper (avoid hipMemsetAsync in capture) ----------------

__global__ void k_zero(unsigned int* __restrict__ p, long n) {
  long i = (long)blockIdx.x * blockDim.x + threadIdx.x;
  if (i < n) p[i] = 0u;
}

__global__ void k_zero_out(float* __restrict__ out, int n) {
  int i = blockIdx.x * blockDim.x + threadIdx.x;
  if (i < n) out[i] = 0.f;
}

// ---------------- dtype prep ----------------

__global__ void k_cvt(const float* __restrict__ x, bf16* __restrict__ xb, long n) {
  long i = (long)blockIdx.x * blockDim.x + threadIdx.x;
  if (i < n) xb[i] = __float2bfloat16(x[i]);
}

// W[K][NN] (f32) -> fragment-packed B2 (bf16).
// Fragment f = k32*(NN/16) + bnG holds the 16x32 tile (cols bnG*16..+16,
// k = k32*32..+32) in MFMA B-operand lane order:
//   B2[f*512 + l*8 + j] = W[k32*32 + (l>>4)*8 + j][bnG*16 + (l&15)]
// so a wave's bfrag load is ONE fully-coalesced 1KB global load (lane*8 elems).
__global__ void k_tw2(const float* __restrict__ W, bf16* __restrict__ B2, int K, int NN) {
  int tid = blockIdx.x * blockDim.x + threadIdx.x;   // one thread per 8 elems
  int total = (K * NN) >> 3;
  if (tid >= total) return;
  int f = tid >> 6, l = tid & 63;
  int nfr = NN >> 4;
  int k32 = f / nfr, bnG = f - k32 * nfr;
  int col = bnG * 16 + (l & 15);
  int krow = k32 * 32 + (l >> 4) * 8;
  s8v v;
#pragma unroll
  for (int j = 0; j < 8; ++j) {
    bf16 b = __float2bfloat16(W[(size_t)(krow + j) * NN + col]);
    v[j] = *(short*)&b;
  }
  *(s8v*)&B2[(size_t)tid * 8] = v;
}

// ---------------- preprocessing: counting-sort edges by dst ----------------

__global__ void k_hist(const int* __restrict__ dst, int* __restrict__ deg, int E, int Et) {
  int e = blockIdx.x * blockDim.x + threadIdx.x;
  if (e >= Et) return;
  int d = (e < E) ? dst[e] : (e - E);   // self-loops appended
  atomicAdd(&deg[d], 1);
}

__global__ void k_hist1(const int* __restrict__ idx, int* __restrict__ deg, int n) {
  int i = blockIdx.x * blockDim.x + threadIdx.x;
  if (i < n) atomicAdd(&deg[idx[i]], 1);
}

__global__ void k_scan1(const int* __restrict__ deg, int* __restrict__ offs,
                        int* __restrict__ bsum, int n) {
  __shared__ int sd[256];
  int t = threadIdx.x;
  int base = blockIdx.x * 1024 + t * 4;
  int v[4]; int tsum = 0;
#pragma unroll
  for (int i = 0; i < 4; ++i) { v[i] = (base + i < n) ? deg[base + i] : 0; tsum += v[i]; }
  sd[t] = tsum;
  __syncthreads();
  for (int off = 1; off < 256; off <<= 1) {
    int x = (t >= off) ? sd[t - off] : 0;
    __syncthreads();
    sd[t] += x;
    __syncthreads();
  }
  int excl = sd[t] - tsum;
#pragma unroll
  for (int i = 0; i < 4; ++i) { if (base + i < n) offs[base + i] = excl; excl += v[i]; }
  if (t == 255) bsum[blockIdx.x] = sd[255];
}

__global__ void k_scan2(int* bsum, int nb) {
  if (threadIdx.x == 0 && blockIdx.x == 0) {
    int run = 0;
    for (int i = 0; i < nb; ++i) { int t = bsum[i]; bsum[i] = run; run += t; }
  }
}

__global__ void k_scan3(int* __restrict__ offs, const int* __restrict__ bsum, int n, int total) {
  int t = threadIdx.x;
  int base = blockIdx.x * 1024 + t * 4;
  int add = bsum[blockIdx.x];
#pragma unroll
  for (int i = 0; i < 4; ++i) if (base + i < n) offs[base + i] += add;
  if (blockIdx.x == 0 && t == 0) offs[n] = total;
}

__global__ void k_scatter(const int* __restrict__ src, const int* __restrict__ dst,
                          const int* __restrict__ offs, int* __restrict__ cur,
                          int* __restrict__ ssrc, int E, int Et) {
  int e = blockIdx.x * blockDim.x + threadIdx.x;
  if (e >= Et) return;
  int s, d;
  if (e < E) { s = src[e]; d = dst[e]; } else { s = d = e - E; }
  int pos = offs[d] + atomicAdd(&cur[d], 1);
  ssrc[pos] = s;
}

// ------- barrier-free direct MFMA GEMM: C[M,NN] = A[M,K] @ W[K,NN] (bf16) -------
// R2's LDS-staged panel kernel was latency-serialized: the per-K-step
// __syncthreads drains vmcnt(0) on the 1-deep global_load_lds prefetch ->
// every step eats full loaded-HBM latency (MfmaUtil 13.5%, VALU 12%, HBM 17%).
// Here: NO LDS, NO barriers. B is pre-packed (k_tw2) so bfrag = one coalesced
// 1KB wave load from the L2-resident weight; afrag loads 16x64B segments
// directly from global (A read once per block). Register double-buffer on
// frags; waves run free, latency hidden by ILP + TLP.
// Block 512t = 8 waves = 2 M-groups (32 rows) x 4 N-groups (NT*16 cols).

template <int NT>
__global__ __launch_bounds__(512) void k_gemm_d(const bf16* __restrict__ A,
                                                const bf16* __restrict__ B2,
                                                bf16* __restrict__ C,
                                                int K, int NN) {
  int t = threadIdx.x;
  int wv = t >> 6, lane = t & 63;
  int mg = wv >> 2, ng = wv & 3;
  int quad = lane >> 4, l15 = lane & 15;
  size_t bm0 = (size_t)blockIdx.x * 64;
  const bf16* Ap0 = A + (bm0 + mg * 32 + l15) * (size_t)K + quad * 8;
  const bf16* Ap1 = Ap0 + (size_t)16 * K;
  int nfr = NN >> 4;
  const bf16* Bp = B2 + ((size_t)(ng * NT) << 9) + lane * 8;
  size_t fstep = (size_t)nfr << 9;          // elems per k32 step

  f4v acc[2][NT];
#pragma unroll
  for (int ms = 0; ms < 2; ++ms)
#pragma unroll
    for (int bn = 0; bn < NT; ++bn) acc[ms][bn] = f4v{0, 0, 0, 0};

  s8v a0 = *(const s8v*)Ap0;
  s8v a1 = *(const s8v*)Ap1;
  s8v bf[NT];
#pragma unroll
  for (int bn = 0; bn < NT; ++bn) bf[bn] = *(const s8v*)(Bp + bn * 512);

  int nk = K >> 5;
  for (int ik = 0; ik < nk; ++ik) {
    int nx = (ik + 1 < nk) ? ik + 1 : ik;   // last iter: reload same (discarded)
    s8v na0 = *(const s8v*)(Ap0 + nx * 32);
    s8v na1 = *(const s8v*)(Ap1 + nx * 32);
    s8v nbf[NT];
#pragma unroll
    for (int bn = 0; bn < NT; ++bn)
      nbf[bn] = *(const s8v*)(Bp + nx * fstep + bn * 512);
#pragma unroll
    for (int bn = 0; bn < NT; ++bn)
      acc[0][bn] = __builtin_amdgcn_mfma_f32_16x16x32_bf16(a0, bf[bn], acc[0][bn], 0, 0, 0);
#pragma unroll
    for (int bn = 0; bn < NT; ++bn)
      acc[1][bn] = __builtin_amdgcn_mfma_f32_16x16x32_bf16(a1, bf[bn], acc[1][bn], 0, 0, 0);
    a0 = na0; a1 = na1;
#pragma unroll
    for (int bn = 0; bn < NT; ++bn) bf[bn] = nbf[bn];
  }

  // C/D layout: col = lane&15, row = quad*4 + reg  [m89/m91 verified]
#pragma unroll
  for (int ms = 0; ms < 2; ++ms)
#pragma unroll
    for (int bn = 0; bn < NT; ++bn) {
      int coln = (ng * NT + bn) * 16 + l15;
      size_t rbase = bm0 + mg * 32 + ms * 16 + quad * 4;
#pragma unroll
      for (int r = 0; r < 4; ++r)
        C[(rbase + r) * NN + coln] = __float2bfloat16(acc[ms][bn][r]);
    }
}

// ---------------- attention logits: one wave per node, 16 lanes per head ----------------
// al_s/al_d stored PADDED to 4 floats per node (H=3) so the per-edge gather in
// k_attn_agg is a single dwordx4 instead of 3 scalar dword gathers.

template <int H>
__global__ void k_al(const bf16* __restrict__ h, const float* __restrict__ as,
                     const float* __restrict__ ad, float* __restrict__ al_s,
                     float* __restrict__ al_d, int N) {
  constexpr int SP = (H > 1) ? 4 : 1;
  int n = (blockIdx.x * blockDim.x + threadIdx.x) >> 6;
  int lane = threadIdx.x & 63;
  if (n >= N) return;
  int hd = lane >> 4;
  bool active = (hd < H);
  int hdc = active ? hd : 0;
  int f8 = (lane & 15) * 8;
  const bf16* hp = h + (size_t)n * (H * 128) + hdc * 128 + f8;
  s8v hv = *(const s8v*)hp;
  float ss = 0.f, sd = 0.f;
#pragma unroll
  for (int i = 0; i < 8; ++i) {
    float v = b2f(hv[i]);
    ss += v * as[hdc * 128 + f8 + i];
    sd += v * ad[hdc * 128 + f8 + i];
  }
#pragma unroll
  for (int off = 8; off; off >>= 1) {
    ss += __shfl_xor(ss, off, 64);
    sd += __shfl_xor(sd, off, 64);
  }
  if (active && (lane & 15) == 0) {
    al_s[n * SP + hd] = ss;
    al_d[n * SP + hd] = sd;
  }
}

// -------- fused segment-softmax + weighted aggregation: one wave per node --------
// (round-0 structure, best measured: 244us/layer). Single pass (online softmax):
// per 64-edge chunk, gather e values (one dwordx4 from padded al_s), wave-reduce
// the chunk max, exp, stash {src, ex[H]} in LDS; serial 8-deep loop reads edge
// records via broadcast ds_read while 8 wide h-row gathers are in flight. Active
// lane owns CPL contiguous channels of one head (48 lanes x 16B for H=3).

template <int CPL> struct HVec;
template <> struct HVec<8> { typedef s8v T; };
template <> struct HVec<4> { typedef s4v T; };

template <int H, typename OT>
__global__ __launch_bounds__(256) void k_attn_agg(const bf16* __restrict__ hbuf,
                           const int* __restrict__ ssrc,
                           const int* __restrict__ offs, const float* __restrict__ al_s,
                           const float* __restrict__ al_d, const float* __restrict__ bias,
                           OT* __restrict__ out, int N) {
  constexpr int SW  = (H > 1) ? 4 : 2;   // stash record (floats)
  constexpr int ROW = H * 128;           // channels per node row
  constexpr int CPL = (H > 1) ? 8 : 4;   // channels per active lane
  constexpr int NL  = ROW / CPL;         // active lanes (48 or 32)
  typedef typename HVec<CPL>::T hvec;

  __shared__ __align__(16) float stash[4][64 * SW];
  int n = (blockIdx.x * blockDim.x + threadIdx.x) >> 6;
  int lane = threadIdx.x & 63;
  if (n >= N) return;
  float* st = stash[threadIdx.x >> 6];
  int start = offs[n], end = offs[n + 1];

  float ald[H];
  if constexpr (H > 1) {
    float4 t = *(const float4*)&al_d[(size_t)n * 4];
    ald[0] = t.x; ald[1] = t.y; ald[2] = t.z;
  } else {
    ald[0] = al_d[n];
  }

  bool act = lane < NL;
  int c0 = act ? lane * CPL : 0;
  int hd_l = c0 >> 7;                    // this lane's head (0 for idle lanes)

  float m[H];
  float den = 0.f;                       // own-head denominator
  float acc[CPL];
#pragma unroll
  for (int hd = 0; hd < H; ++hd) m[hd] = -1e30f;
#pragma unroll
  for (int i = 0; i < CPL; ++i) acc[i] = 0.f;

  for (int cb = start; cb < end; cb += 64) {
    int cl = end - cb; if (cl > 64) cl = 64;
    bool el = lane < cl;
    int mys = el ? ssrc[cb + lane] : 0;
    float ev[H];
    if constexpr (H > 1) {
      float4 av = *(const float4*)&al_s[(size_t)mys * 4];
      ev[0] = av.x; ev[1] = av.y; ev[2] = av.z;
    } else {
      ev[0] = al_s[mys];
    }
#pragma unroll
    for (int hd = 0; hd < H; ++hd)
      ev[hd] = el ? lrelu(ev[hd] + ald[hd]) : -1e30f;

    // chunk max (fused -- no separate max pass over the edges)
    float nm[H];
#pragma unroll
    for (int hd = 0; hd < H; ++hd) {
      float v = ev[hd];
#pragma unroll
      for (int off = 32; off; off >>= 1) v = fmaxf(v, __shfl_xor(v, off, 64));
      nm[hd] = fmaxf(v, m[hd]);
    }
    if (cb > start) {                    // online rescale; wave-uniform branch
      float sc[H];
#pragma unroll
      for (int hd = 0; hd < H; ++hd) sc[hd] = __expf(m[hd] - nm[hd]);
      float so = sc[hd_l];
      den *= so;
#pragma unroll
      for (int i = 0; i < CPL; ++i) acc[i] *= so;
    }
#pragma unroll
    for (int hd = 0; hd < H; ++hd) m[hd] = nm[hd];

    float myex[H];
#pragma unroll
    for (int hd = 0; hd < H; ++hd) myex[hd] = el ? __expf(ev[hd] - m[hd]) : 0.f;

    // stash this chunk's edge records (wave-private region; wave-synchronous)
    __builtin_amdgcn_wave_barrier();
    if constexpr (H > 1) {
      float4 s4{__int_as_float(mys), myex[0], myex[1], myex[2]};
      *(float4*)&st[lane * 4] = s4;
    } else {
      float2 s2{__int_as_float(mys), myex[0]};
      *(float2*)&st[lane * 2] = s2;
    }
    asm volatile("s_waitcnt lgkmcnt(0)" ::: "memory");
    __builtin_amdgcn_wave_barrier();

    for (int r = 0; r < cl; r += 8) {
      int su[8]; float a[8];
#pragma unroll
      for (int u = 0; u < 8; ++u) {
        if constexpr (H > 1) {
          float4 ed = *(const float4*)&st[(r + u) * 4];   // broadcast ds_read_b128
          su[u] = __float_as_int(ed.x);
          a[u] = (hd_l == 0) ? ed.y : ((hd_l == 1) ? ed.z : ed.w);
        } else {
          float2 ed = *(const float2*)&st[(r + u) * 2];
          su[u] = __float_as_int(ed.x);
          a[u] = ed.y;
        }
        den += a[u];                     // tail slots stash a==0
      }
      hvec hv[8];
#pragma unroll
      for (int u = 0; u < 8; ++u)
        hv[u] = *(const hvec*)(hbuf + (size_t)su[u] * ROW + c0);
#pragma unroll
      for (int u = 0; u < 8; ++u)
#pragma unroll
        for (int i = 0; i < CPL; ++i)
          acc[i] += a[u] * b2f(hv[u][i]);
    }
  }

  if (act) {
    float rr = 1.f / (den + 1e-16f);
    OT* op = out + (size_t)n * ROW + c0;
    if constexpr (sizeof(OT) == 2) {
      s8v ov;
#pragma unroll
      for (int i = 0; i < CPL; ++i) {
        float o = lrelu(acc[i] * rr + bias[c0 + i]);
        bf16 b = __float2bfloat16(o);
        ov[i] = *(short*)&b;
      }
      nt_store16(op, ov);
    } else {
      float4 ov;
      ov.x = lrelu(acc[0] * rr + bias[c0 + 0]);
      ov.y = lrelu(acc[1] * rr + bias[c0 + 1]);
      ov.z = lrelu(acc[2] * rr + bias[c0 + 2]);
      ov.w = lrelu(acc[3] * rr + bias[c0 + 3]);
      nt_store16(op, ov);
    }
  }
}

// ---------------- global mean pool: one wave per graph, no atomics ----------------

__global__ void k_pool(const float* __restrict__ h, const int* __restrict__ goffs,
                       float* __restrict__ out, int G) {
  int g = (blockIdx.x * blockDim.x + threadIdx.x) >> 6;
  int lane = threadIdx.x & 63;
  if (g >= G) return;
  int s = goffs[g], e = goffs[g + 1];
  float ax = 0.f, ay = 0.f;
  for (int n = s; n < e; ++n) {
    float2 v = *(const float2*)&h[(size_t)n * 128 + lane * 2];
    ax += v.x; ay += v.y;
  }
  float c = fmaxf((float)(e - s), 1.f);
  st2(&out[(size_t)g * 128 + lane * 2], ax / c, ay / c);
}

// ---------------- host launcher ----------------

extern "C" void kernel_launch(void* const* d_in, const int* in_sizes, int n_in,
                              void* d_out, int out_size, void* d_ws, size_t ws_size,
                              hipStream_t stream) {
  const float* x   = (const float*)d_in[0];
  const int*   ei  = (const int*)d_in[1];
  const int*   bat = (const int*)d_in[2];
  const float* W1  = (const float*)d_in[3];
  const float* a1s = (const float*)d_in[4];
  const float* a1d = (const float*)d_in[5];
  const float* b1  = (const float*)d_in[6];
  const float* W2  = (const float*)d_in[7];
  const float* a2s = (const float*)d_in[8];
  const float* a2d = (const float*)d_in[9];
  const float* b2  = (const float*)d_in[10];
  const float* W3  = (const float*)d_in[11];
  const float* a3s = (const float*)d_in[12];
  const float* a3d = (const float*)d_in[13];
  const float* b3  = (const float*)d_in[14];
  float* out = (float*)d_out;

  const int N = in_sizes[2];          // 200000
  const int E = in_sizes[1] / 2;      // 1600000
  const int Et = E + N;               // with self-loops
  const int G = out_size / 128;       // 5000

  // ---- workspace carve (bf16 intermediates) ----
  char* p = (char*)d_ws;
  auto carve = [&](size_t bytes) { void* r = (void*)p; p += (bytes + 255) & ~(size_t)255; return r; };
  bf16*  bufA   = (bf16*)carve((size_t)N * 384 * 2);   // agg out / GEMM A; also hosts xb & fp32 layer-3 out
  bf16*  bufB   = (bf16*)carve((size_t)N * 384 * 2);   // GEMM output h
  float* al_s   = (float*)carve((size_t)N * 4 * 4);    // padded to 4 floats/node
  float* al_d   = (float*)carve((size_t)N * 4 * 4);
  int*   ssrc   = (int*)carve((size_t)Et * 4);
  int*   offs   = (int*)carve((size_t)(N + 1) * 4);
  int*   deg    = (int*)carve((size_t)N * 4);
  int*   cur    = (int*)carve((size_t)N * 4);
  int*   bsum   = (int*)carve(4096 * 4);
  int*   gdeg   = (int*)carve((size_t)G * 4);
  int*   goffs  = (int*)carve((size_t)(G + 1) * 4);
  bf16*  Wp1    = (bf16*)carve((size_t)384 * 128 * 2);   // packed B2 buffers
  bf16*  Wp2    = (bf16*)carve((size_t)384 * 384 * 2);
  bf16*  Wp3    = (bf16*)carve((size_t)128 * 384 * 2);
  size_t need = (size_t)(p - (char*)d_ws);

  if (ws_size < need) {
    k_zero_out<<<(out_size + 255) / 256, 256, 0, stream>>>(out, out_size);
    return;
  }

  const int* esrc = ei;
  const int* edst = ei + E;

  int ebl = (Et + 255) / 256;
  int NB = (N + 1023) / 1024;
  int GB = (G + 1023) / 1024;
  int nodeWaveBlocks = (N * 64 + 255) / 256;
  int gemmBlocks = (N + 63) / 64;

  // ---- prep: weight pack+cast, x cast (xb aliases bufA) ----
  bf16* xb = bufA;
  k_cvt<<<((long)N * 128 + 255) / 256, 256, 0, stream>>>(x, xb, (long)N * 128);
  k_tw2<<<(128 * 384 / 8 + 255) / 256, 256, 0, stream>>>(W1, Wp1, 128, 384);
  k_tw2<<<(384 * 384 / 8 + 255) / 256, 256, 0, stream>>>(W2, Wp2, 384, 384);
  k_tw2<<<(384 * 128 / 8 + 255) / 256, 256, 0, stream>>>(W3, Wp3, 384, 128);

  // ---- sort edges by dst ----
  k_zero<<<(N + 255) / 256, 256, 0, stream>>>((unsigned int*)deg, N);
  k_hist<<<ebl, 256, 0, stream>>>(edst, deg, E, Et);
  k_scan1<<<NB, 256, 0, stream>>>(deg, offs, bsum, N);
  k_scan2<<<1, 64, 0, stream>>>(bsum, NB);
  k_scan3<<<NB, 256, 0, stream>>>(offs, bsum, N, Et);
  k_zero<<<(N + 255) / 256, 256, 0, stream>>>((unsigned int*)cur, N);
  k_scatter<<<ebl, 256, 0, stream>>>(esrc, edst, offs, cur, ssrc, E, Et);

  // ---- graph offsets for pool (batch is sorted) ----
  k_zero<<<(G + 255) / 256, 256, 0, stream>>>((unsigned int*)gdeg, G);
  k_hist1<<<(N + 255) / 256, 256, 0, stream>>>(bat, gdeg, N);
  k_scan1<<<GB, 256, 0, stream>>>(gdeg, goffs, bsum, G);
  k_scan2<<<1, 64, 0, stream>>>(bsum, GB);
  k_scan3<<<GB, 256, 0, stream>>>(goffs, bsum, G, N);

  // ---- layer 1: xb[N,128] @ W1 -> bufB[N,384] ----
  k_gemm_d<6><<<gemmBlocks, 512, 0, stream>>>(xb, Wp1, bufB, 128, 384);
  k_al<3><<<nodeWaveBlocks, 256, 0, stream>>>(bufB, a1s, a1d, al_s, al_d, N);
  k_attn_agg<3, bf16><<<nodeWaveBlocks, 256, 0, stream>>>(bufB, ssrc, offs, al_s, al_d, b1, bufA, N);

  // ---- layer 2: bufA[N,384] @ W2 -> bufB[N,384] ----
  k_gemm_d<6><<<gemmBlocks, 512, 0, stream>>>(bufA, Wp2, bufB, 384, 384);
  k_al<3><<<nodeWaveBlocks, 256, 0, stream>>>(bufB, a2s, a2d, al_s, al_d, N);
  k_attn_agg<3, bf16><<<nodeWaveBlocks, 256, 0, stream>>>(bufB, ssrc, offs, al_s, al_d, b2, bufA, N);

  // ---- layer 3: bufA[N,384] @ W3 -> bufB[N,128], heads=1, fp32 agg out ----
  k_gemm_d<2><<<gemmBlocks, 512, 0, stream>>>(bufA, Wp3, bufB, 384, 128);
  k_al<1><<<nodeWaveBlocks, 256, 0, stream>>>(bufB, a3s, a3d, al_s, al_d, N);
  float* out3 = (float*)bufA;
  k_attn_agg<1, float><<<nodeWaveBlocks, 256, 0, stream>>>(bufB, ssrc, offs, al_s, al_d, b3, out3, N);

  // ---- global mean pool: segmented, atomic-free ----
  k_pool<<<(G * 64 + 255) / 256, 256, 0, stream>>>(out3, goffs, out, G);
}

// Round 5
// 1503.069 us; speedup vs baseline: 1.0992x; 1.0055x over previous
//
#include <hip/hip_runtime.h>
#include <hip/hip_bf16.h>
#include <math.h>

#define LRELU_SLOPE 0.2f
typedef __hip_bfloat16 bf16;
typedef __hip_bfloat162 bf16x2;

typedef short s8v __attribute__((ext_vector_type(8)));   // 8 bf16 (4 VGPRs)
typedef short s4v __attribute__((ext_vector_type(4)));   // 4 bf16 (2 VGPRs)
typedef float f4v __attribute__((ext_vector_type(4)));   // MFMA acc
typedef int   i4v __attribute__((ext_vector_type(4)));
typedef unsigned int u4v __attribute__((ext_vector_type(4)));

__device__ __forceinline__ float lrelu(float v) { return v > 0.f ? v : LRELU_SLOPE * v; }
__device__ __forceinline__ float b2f(short b) {
  return __uint_as_float(((unsigned)(unsigned short)b) << 16);
}

__device__ __forceinline__ void st2(float* p, float x, float y) {
  *(float2*)p = float2{x, y};
}

// ---- streaming store that bypasses L2/MALL allocation (sc1 + nt) ----
// The agg output (150 MB/dispatch) was write-allocating in the 256 MB L3 and
// thrashing the 154 MB h gather set (FETCH = 5x the h buffer). All consumers
// of these outputs are streaming readers, so no locality is lost.
__device__ __forceinline__ u4v make_srd(const void* p) {
  u4v r;
  unsigned long long a = (unsigned long long)p;
  r.x = (unsigned)a; r.y = (unsigned)(a >> 32);
  r.z = 0xFFFFFFFFu;          // num_records: disable bounds check
  r.w = 0x00020000u;          // raw dword access
  return r;
}
__device__ __forceinline__ void bstore16_nt(u4v srd, int byteoff, i4v d) {
  asm volatile("buffer_store_dwordx4 %0, %1, %2, 0 offen sc1 nt"
               :: "v"(d), "v"(byteoff), "s"(srd));
}

// ---------------- zero helper (avoid hipMemsetAsync in capture) ----------------

__global__ void k_zero(unsigned int* __restrict__ p, long n) {
  long i = (long)blockIdx.x * blockDim.x + threadIdx.x;
  if (i < n) p[i] = 0u;
}

__global__ void k_zero_out(float* __restrict__ out, int n) {
  int i = blockIdx.x * blockDim.x + threadIdx.x;
  if (i < n) out[i] = 0.f;
}

// ---------------- dtype prep ----------------

__global__ void k_cvt(const float* __restrict__ x, bf16* __restrict__ xb, long n) {
  long i = (long)blockIdx.x * blockDim.x + threadIdx.x;
  if (i < n) xb[i] = __float2bfloat16(x[i]);
}

// W[K][NN] (f32) -> fragment-packed B2 (bf16).
// Fragment f = k32*(NN/16) + bnG holds the 16x32 tile (cols bnG*16..+16,
// k = k32*32..+32) in MFMA B-operand lane order:
//   B2[f*512 + l*8 + j] = W[k32*32 + (l>>4)*8 + j][bnG*16 + (l&15)]
// so a wave's bfrag load is ONE fully-coalesced 1KB global load (lane*8 elems).
__global__ void k_tw2(const float* __restrict__ W, bf16* __restrict__ B2, int K, int NN) {
  int tid = blockIdx.x * blockDim.x + threadIdx.x;   // one thread per 8 elems
  int total = (K * NN) >> 3;
  if (tid >= total) return;
  int f = tid >> 6, l = tid & 63;
  int nfr = NN >> 4;
  int k32 = f / nfr, bnG = f - k32 * nfr;
  int col = bnG * 16 + (l & 15);
  int krow = k32 * 32 + (l >> 4) * 8;
  s8v v;
#pragma unroll
  for (int j = 0; j < 8; ++j) {
    bf16 b = __float2bfloat16(W[(size_t)(krow + j) * NN + col]);
    v[j] = *(short*)&b;
  }
  *(s8v*)&B2[(size_t)tid * 8] = v;
}

// ---------------- preprocessing: counting-sort edges by dst ----------------

__global__ void k_hist(const int* __restrict__ dst, int* __restrict__ deg, int E, int Et) {
  int e = blockIdx.x * blockDim.x + threadIdx.x;
  if (e >= Et) return;
  int d = (e < E) ? dst[e] : (e - E);   // self-loops appended
  atomicAdd(&deg[d], 1);
}

__global__ void k_hist1(const int* __restrict__ idx, int* __restrict__ deg, int n) {
  int i = blockIdx.x * blockDim.x + threadIdx.x;
  if (i < n) atomicAdd(&deg[idx[i]], 1);
}

__global__ void k_scan1(const int* __restrict__ deg, int* __restrict__ offs,
                        int* __restrict__ bsum, int n) {
  __shared__ int sd[256];
  int t = threadIdx.x;
  int base = blockIdx.x * 1024 + t * 4;
  int v[4]; int tsum = 0;
#pragma unroll
  for (int i = 0; i < 4; ++i) { v[i] = (base + i < n) ? deg[base + i] : 0; tsum += v[i]; }
  sd[t] = tsum;
  __syncthreads();
  for (int off = 1; off < 256; off <<= 1) {
    int x = (t >= off) ? sd[t - off] : 0;
    __syncthreads();
    sd[t] += x;
    __syncthreads();
  }
  int excl = sd[t] - tsum;
#pragma unroll
  for (int i = 0; i < 4; ++i) { if (base + i < n) offs[base + i] = excl; excl += v[i]; }
  if (t == 255) bsum[blockIdx.x] = sd[255];
}

// parallel exclusive scan over block sums (nb <= 256 here; serial fallback else).
// Replaces the old 1-thread loop: 196 dependent global round-trips ~= 55 us.
__global__ void k_scan2(int* bsum, int nb) {
  int t = threadIdx.x;
  if (nb > 256) {
    if (t == 0 && blockIdx.x == 0) {
      int run = 0;
      for (int i = 0; i < nb; ++i) { int x = bsum[i]; bsum[i] = run; run += x; }
    }
    return;
  }
  int v = (t < nb) ? bsum[t] : 0;
  int lane = t & 63, wv = t >> 6;
  int s = v;
#pragma unroll
  for (int off = 1; off < 64; off <<= 1) {
    int u = __shfl_up(s, off, 64);
    if (lane >= off) s += u;
  }
  __shared__ int wsum[4];
  if (lane == 63) wsum[wv] = s;
  __syncthreads();
  int add = 0;
  for (int w = 0; w < wv; ++w) add += wsum[w];
  if (t < nb) bsum[t] = add + s - v;   // exclusive
}

__global__ void k_scan3(int* __restrict__ offs, const int* __restrict__ bsum, int n, int total) {
  int t = threadIdx.x;
  int base = blockIdx.x * 1024 + t * 4;
  int add = bsum[blockIdx.x];
#pragma unroll
  for (int i = 0; i < 4; ++i) if (base + i < n) offs[base + i] += add;
  if (blockIdx.x == 0 && t == 0) offs[n] = total;
}

__global__ void k_scatter(const int* __restrict__ src, const int* __restrict__ dst,
                          const int* __restrict__ offs, int* __restrict__ cur,
                          int* __restrict__ ssrc, int E, int Et) {
  int e = blockIdx.x * blockDim.x + threadIdx.x;
  if (e >= Et) return;
  int s, d;
  if (e < E) { s = src[e]; d = dst[e]; } else { s = d = e - E; }
  int pos = offs[d] + atomicAdd(&cur[d], 1);
  ssrc[pos] = s;
}

// ------- barrier-free direct MFMA GEMM, depth-3 register pipeline -------
// C[M,NN] = A[M,K] @ W[K,NN] (bf16). No LDS, no barriers. B pre-packed (k_tw2)
// so bfrag = one coalesced 1KB wave load (L2-resident weights); A loads direct
// from global. R3's version was effectively 1-deep prefetch -> each K-step
// exposed A latency (~600-900 cyc) against ~60 cyc of MFMA. Now: K/NN are
// template params -> nk constexpr -> FULL unroll with 3 named register slots
// (all indices static, no scratch), loads issued 3 K-steps ahead. In-flight
// bytes/CU >> Little's-law requirement -> BW-bound, not latency-bound.
// Block 512t = 8 waves = 2 M-groups (32 rows) x 4 N-groups (NT*16 cols).

template <int NT, int K, int NN>
__global__ __launch_bounds__(512) void k_gemm_d(const bf16* __restrict__ A,
                                                const bf16* __restrict__ B2,
                                                bf16* __restrict__ C) {
  constexpr int nk = K >> 5;
  int t = threadIdx.x;
  int wv = t >> 6, lane = t & 63;
  int mg = wv >> 2, ng = wv & 3;
  int quad = lane >> 4, l15 = lane & 15;
  size_t bm0 = (size_t)blockIdx.x * 64;
  const bf16* Ap0 = A + (bm0 + mg * 32 + l15) * (size_t)K + quad * 8;
  const bf16* Ap1 = Ap0 + (size_t)16 * K;
  constexpr int nfr = NN >> 4;
  const bf16* Bp = B2 + ((size_t)(ng * NT) << 9) + lane * 8;
  constexpr size_t fstep = (size_t)nfr << 9;          // elems per k32 step

  f4v acc[2][NT];
#pragma unroll
  for (int ms = 0; ms < 2; ++ms)
#pragma unroll
    for (int bn = 0; bn < NT; ++bn) acc[ms][bn] = f4v{0, 0, 0, 0};

  s8v pa0[3], pa1[3], pb[3][NT];
#define GLOAD(ik, sl)                                                        \
  do {                                                                       \
    pa0[sl] = *(const s8v*)(Ap0 + (ik) * 32);                                \
    pa1[sl] = *(const s8v*)(Ap1 + (ik) * 32);                                \
    _Pragma("unroll")                                                        \
    for (int bn = 0; bn < NT; ++bn)                                          \
      pb[sl][bn] = *(const s8v*)(Bp + (ik) * fstep + bn * 512);              \
  } while (0)

  GLOAD(0, 0);
  if constexpr (nk > 1) GLOAD(1, 1);
  if constexpr (nk > 2) GLOAD(2, 2);

#pragma unroll
  for (int ik = 0; ik < nk; ++ik) {
    const int c = ik % 3;                // static under full unroll
#pragma unroll
    for (int bn = 0; bn < NT; ++bn)
      acc[0][bn] = __builtin_amdgcn_mfma_f32_16x16x32_bf16(pa0[c], pb[c][bn], acc[0][bn], 0, 0, 0);
#pragma unroll
    for (int bn = 0; bn < NT; ++bn)
      acc[1][bn] = __builtin_amdgcn_mfma_f32_16x16x32_bf16(pa1[c], pb[c][bn], acc[1][bn], 0, 0, 0);
    if (ik + 3 < nk) GLOAD(ik + 3, c);   // refill the slot just consumed
  }
#undef GLOAD

  // C/D layout: col = lane&15, row = quad*4 + reg  [m89/m91 verified]
  // C stores stay DEFAULT (allocate): bufB is the next gather's hot set.
#pragma unroll
  for (int ms = 0; ms < 2; ++ms)
#pragma unroll
    for (int bn = 0; bn < NT; ++bn) {
      int coln = (ng * NT + bn) * 16 + l15;
      size_t rbase = bm0 + mg * 32 + ms * 16 + quad * 4;
#pragma unroll
      for (int r = 0; r < 4; ++r)
        C[(rbase + r) * NN + coln] = __float2bfloat16(acc[ms][bn][r]);
    }
}

// ---------------- attention logits: one wave per node, 16 lanes per head ----------------
// al_s/al_d stored PADDED to 4 floats per node (H=3) so the per-edge gather in
// k_attn_agg is a single dwordx4 instead of 3 scalar dword gathers.

template <int H>
__global__ void k_al(const bf16* __restrict__ h, const float* __restrict__ as,
                     const float* __restrict__ ad, float* __restrict__ al_s,
                     float* __restrict__ al_d, int N) {
  constexpr int SP = (H > 1) ? 4 : 1;
  int n = (blockIdx.x * blockDim.x + threadIdx.x) >> 6;
  int lane = threadIdx.x & 63;
  if (n >= N) return;
  int hd = lane >> 4;
  bool active = (hd < H);
  int hdc = active ? hd : 0;
  int f8 = (lane & 15) * 8;
  const bf16* hp = h + (size_t)n * (H * 128) + hdc * 128 + f8;
  s8v hv = *(const s8v*)hp;
  float ss = 0.f, sd = 0.f;
#pragma unroll
  for (int i = 0; i < 8; ++i) {
    float v = b2f(hv[i]);
    ss += v * as[hdc * 128 + f8 + i];
    sd += v * ad[hdc * 128 + f8 + i];
  }
#pragma unroll
  for (int off = 8; off; off >>= 1) {
    ss += __shfl_xor(ss, off, 64);
    sd += __shfl_xor(sd, off, 64);
  }
  if (active && (lane & 15) == 0) {
    al_s[n * SP + hd] = ss;
    al_d[n * SP + hd] = sd;
  }
}

// -------- fused segment-softmax + weighted aggregation: one wave per node --------
// (round-0 structure, best measured). Single pass (online softmax): per 64-edge
// chunk, gather e values (one dwordx4 from padded al_s), wave-reduce the chunk
// max, exp, stash {src, ex[H]} in LDS; serial 8-deep loop reads edge records
// via broadcast ds_read while 8 wide h-row gathers are in flight. Active lane
// owns CPL contiguous channels of one head (48 lanes x 16B for H=3).
// Output stores: buffer_store sc1 nt (bypass L2/MALL) -- see make_srd comment.

template <int CPL> struct HVec;
template <> struct HVec<8> { typedef s8v T; };
template <> struct HVec<4> { typedef s4v T; };

template <int H, typename OT>
__global__ __launch_bounds__(256) void k_attn_agg(const bf16* __restrict__ hbuf,
                           const int* __restrict__ ssrc,
                           const int* __restrict__ offs, const float* __restrict__ al_s,
                           const float* __restrict__ al_d, const float* __restrict__ bias,
                           OT* __restrict__ out, int N) {
  constexpr int SW  = (H > 1) ? 4 : 2;   // stash record (floats)
  constexpr int ROW = H * 128;           // channels per node row
  constexpr int CPL = (H > 1) ? 8 : 4;   // channels per active lane
  constexpr int NL  = ROW / CPL;         // active lanes (48 or 32)
  typedef typename HVec<CPL>::T hvec;

  __shared__ __align__(16) float stash[4][64 * SW];
  int n = (blockIdx.x * blockDim.x + threadIdx.x) >> 6;
  int lane = threadIdx.x & 63;
  if (n >= N) return;
  float* st = stash[threadIdx.x >> 6];
  int start = offs[n], end = offs[n + 1];

  float ald[H];
  if constexpr (H > 1) {
    float4 t = *(const float4*)&al_d[(size_t)n * 4];
    ald[0] = t.x; ald[1] = t.y; ald[2] = t.z;
  } else {
    ald[0] = al_d[n];
  }

  bool act = lane < NL;
  int c0 = act ? lane * CPL : 0;
  int hd_l = c0 >> 7;                    // this lane's head (0 for idle lanes)

  float m[H];
  float den = 0.f;                       // own-head denominator
  float acc[CPL];
#pragma unroll
  for (int hd = 0; hd < H; ++hd) m[hd] = -1e30f;
#pragma unroll
  for (int i = 0; i < CPL; ++i) acc[i] = 0.f;

  for (int cb = start; cb < end; cb += 64) {
    int cl = end - cb; if (cl > 64) cl = 64;
    bool el = lane < cl;
    int mys = el ? ssrc[cb + lane] : 0;
    float ev[H];
    if constexpr (H > 1) {
      float4 av = *(const float4*)&al_s[(size_t)mys * 4];
      ev[0] = av.x; ev[1] = av.y; ev[2] = av.z;
    } else {
      ev[0] = al_s[mys];
    }
#pragma unroll
    for (int hd = 0; hd < H; ++hd)
      ev[hd] = el ? lrelu(ev[hd] + ald[hd]) : -1e30f;

    // chunk max (fused -- no separate max pass over the edges)
    float nm[H];
#pragma unroll
    for (int hd = 0; hd < H; ++hd) {
      float v = ev[hd];
#pragma unroll
      for (int off = 32; off; off >>= 1) v = fmaxf(v, __shfl_xor(v, off, 64));
      nm[hd] = fmaxf(v, m[hd]);
    }
    if (cb > start) {                    // online rescale; wave-uniform branch
      float sc[H];
#pragma unroll
      for (int hd = 0; hd < H; ++hd) sc[hd] = __expf(m[hd] - nm[hd]);
      float so = sc[hd_l];
      den *= so;
#pragma unroll
      for (int i = 0; i < CPL; ++i) acc[i] *= so;
    }
#pragma unroll
    for (int hd = 0; hd < H; ++hd) m[hd] = nm[hd];

    float myex[H];
#pragma unroll
    for (int hd = 0; hd < H; ++hd) myex[hd] = el ? __expf(ev[hd] - m[hd]) : 0.f;

    // stash this chunk's edge records (wave-private region; wave-synchronous)
    __builtin_amdgcn_wave_barrier();
    if constexpr (H > 1) {
      float4 s4{__int_as_float(mys), myex[0], myex[1], myex[2]};
      *(float4*)&st[lane * 4] = s4;
    } else {
      float2 s2{__int_as_float(mys), myex[0]};
      *(float2*)&st[lane * 2] = s2;
    }
    asm volatile("s_waitcnt lgkmcnt(0)" ::: "memory");
    __builtin_amdgcn_wave_barrier();

    for (int r = 0; r < cl; r += 8) {
      int su[8]; float a[8];
#pragma unroll
      for (int u = 0; u < 8; ++u) {
        if constexpr (H > 1) {
          float4 ed = *(const float4*)&st[(r + u) * 4];   // broadcast ds_read_b128
          su[u] = __float_as_int(ed.x);
          a[u] = (hd_l == 0) ? ed.y : ((hd_l == 1) ? ed.z : ed.w);
        } else {
          float2 ed = *(const float2*)&st[(r + u) * 2];
          su[u] = __float_as_int(ed.x);
          a[u] = ed.y;
        }
        den += a[u];                     // tail slots stash a==0
      }
      hvec hv[8];
#pragma unroll
      for (int u = 0; u < 8; ++u)
        hv[u] = *(const hvec*)(hbuf + (size_t)su[u] * ROW + c0);
#pragma unroll
      for (int u = 0; u < 8; ++u)
#pragma unroll
        for (int i = 0; i < CPL; ++i)
          acc[i] += a[u] * b2f(hv[u][i]);
    }
  }

  if (act) {
    float rr = 1.f / (den + 1e-16f);
    u4v srd = make_srd(out);
    int boff = (int)(((size_t)n * ROW + c0) * sizeof(OT));
    if constexpr (sizeof(OT) == 2) {
      union { s8v s; i4v i; } u;
#pragma unroll
      for (int i = 0; i < CPL; ++i) {
        float o = lrelu(acc[i] * rr + bias[c0 + i]);
        bf16 b = __float2bfloat16(o);
        u.s[i] = *(short*)&b;
      }
      bstore16_nt(srd, boff, u.i);
    } else {
      union { float4 f; i4v i; } u;
      u.f.x = lrelu(acc[0] * rr + bias[c0 + 0]);
      u.f.y = lrelu(acc[1] * rr + bias[c0 + 1]);
      u.f.z = lrelu(acc[2] * rr + bias[c0 + 2]);
      u.f.w = lrelu(acc[3] * rr + bias[c0 + 3]);
      bstore16_nt(srd, boff, u.i);
    }
  }
}

// ---------------- global mean pool: one wave per graph, no atomics ----------------

__global__ void k_pool(const float* __restrict__ h, const int* __restrict__ goffs,
                       float* __restrict__ out, int G) {
  int g = (blockIdx.x * blockDim.x + threadIdx.x) >> 6;
  int lane = threadIdx.x & 63;
  if (g >= G) return;
  int s = goffs[g], e = goffs[g + 1];
  float ax = 0.f, ay = 0.f;
  for (int n = s; n < e; ++n) {
    float2 v = *(const float2*)&h[(size_t)n * 128 + lane * 2];
    ax += v.x; ay += v.y;
  }
  float c = fmaxf((float)(e - s), 1.f);
  st2(&out[(size_t)g * 128 + lane * 2], ax / c, ay / c);
}

// ---------------- host launcher ----------------

extern "C" void kernel_launch(void* const* d_in, const int* in_sizes, int n_in,
                              void* d_out, int out_size, void* d_ws, size_t ws_size,
                              hipStream_t stream) {
  const float* x   = (const float*)d_in[0];
  const int*   ei  = (const int*)d_in[1];
  const int*   bat = (const int*)d_in[2];
  const float* W1  = (const float*)d_in[3];
  const float* a1s = (const float*)d_in[4];
  const float* a1d = (const float*)d_in[5];
  const float* b1  = (const float*)d_in[6];
  const float* W2  = (const float*)d_in[7];
  const float* a2s = (const float*)d_in[8];
  const float* a2d = (const float*)d_in[9];
  const float* b2  = (const float*)d_in[10];
  const float* W3  = (const float*)d_in[11];
  const float* a3s = (const float*)d_in[12];
  const float* a3d = (const float*)d_in[13];
  const float* b3  = (const float*)d_in[14];
  float* out = (float*)d_out;

  const int N = in_sizes[2];          // 200000
  const int E = in_sizes[1] / 2;      // 1600000
  const int Et = E + N;               // with self-loops
  const int G = out_size / 128;       // 5000

  // ---- workspace carve (bf16 intermediates) ----
  char* p = (char*)d_ws;
  auto carve = [&](size_t bytes) { void* r = (void*)p; p += (bytes + 255) & ~(size_t)255; return r; };
  bf16*  bufA   = (bf16*)carve((size_t)N * 384 * 2);   // agg out / GEMM A; also hosts xb & fp32 layer-3 out
  bf16*  bufB   = (bf16*)carve((size_t)N * 384 * 2);   // GEMM output h
  float* al_s   = (float*)carve((size_t)N * 4 * 4);    // padded to 4 floats/node
  float* al_d   = (float*)carve((size_t)N * 4 * 4);
  int*   ssrc   = (int*)carve((size_t)Et * 4);
  int*   offs   = (int*)carve((size_t)(N + 1) * 4);
  int*   deg    = (int*)carve((size_t)N * 4);
  int*   cur    = (int*)carve((size_t)N * 4);
  int*   bsum   = (int*)carve(4096 * 4);
  int*   gdeg   = (int*)carve((size_t)G * 4);
  int*   goffs  = (int*)carve((size_t)(G + 1) * 4);
  bf16*  Wp1    = (bf16*)carve((size_t)384 * 128 * 2);   // packed B2 buffers
  bf16*  Wp2    = (bf16*)carve((size_t)384 * 384 * 2);
  bf16*  Wp3    = (bf16*)carve((size_t)128 * 384 * 2);
  size_t need = (size_t)(p - (char*)d_ws);

  if (ws_size < need) {
    k_zero_out<<<(out_size + 255) / 256, 256, 0, stream>>>(out, out_size);
    return;
  }

  const int* esrc = ei;
  const int* edst = ei + E;

  int ebl = (Et + 255) / 256;
  int NB = (N + 1023) / 1024;
  int GB = (G + 1023) / 1024;
  int nodeWaveBlocks = (N * 64 + 255) / 256;
  int gemmBlocks = (N + 63) / 64;

  // ---- prep: weight pack+cast, x cast (xb aliases bufA) ----
  bf16* xb = bufA;
  k_cvt<<<((long)N * 128 + 255) / 256, 256, 0, stream>>>(x, xb, (long)N * 128);
  k_tw2<<<(128 * 384 / 8 + 255) / 256, 256, 0, stream>>>(W1, Wp1, 128, 384);
  k_tw2<<<(384 * 384 / 8 + 255) / 256, 256, 0, stream>>>(W2, Wp2, 384, 384);
  k_tw2<<<(384 * 128 / 8 + 255) / 256, 256, 0, stream>>>(W3, Wp3, 384, 128);

  // ---- sort edges by dst ----
  k_zero<<<(N + 255) / 256, 256, 0, stream>>>((unsigned int*)deg, N);
  k_hist<<<ebl, 256, 0, stream>>>(edst, deg, E, Et);
  k_scan1<<<NB, 256, 0, stream>>>(deg, offs, bsum, N);
  k_scan2<<<1, 256, 0, stream>>>(bsum, NB);
  k_scan3<<<NB, 256, 0, stream>>>(offs, bsum, N, Et);
  k_zero<<<(N + 255) / 256, 256, 0, stream>>>((unsigned int*)cur, N);
  k_scatter<<<ebl, 256, 0, stream>>>(esrc, edst, offs, cur, ssrc, E, Et);

  // ---- graph offsets for pool (batch is sorted) ----
  k_zero<<<(G + 255) / 256, 256, 0, stream>>>((unsigned int*)gdeg, G);
  k_hist1<<<(N + 255) / 256, 256, 0, stream>>>(bat, gdeg, N);
  k_scan1<<<GB, 256, 0, stream>>>(gdeg, goffs, bsum, G);
  k_scan2<<<1, 256, 0, stream>>>(bsum, GB);
  k_scan3<<<GB, 256, 0, stream>>>(goffs, bsum, G, N);

  // ---- layer 1: xb[N,128] @ W1 -> bufB[N,384] ----
  k_gemm_d<6, 128, 384><<<gemmBlocks, 512, 0, stream>>>(xb, Wp1, bufB);
  k_al<3><<<nodeWaveBlocks, 256, 0, stream>>>(bufB, a1s, a1d, al_s, al_d, N);
  k_attn_agg<3, bf16><<<nodeWaveBlocks, 256, 0, stream>>>(bufB, ssrc, offs, al_s, al_d, b1, bufA, N);

  // ---- layer 2: bufA[N,384] @ W2 -> bufB[N,384] ----
  k_gemm_d<6, 384, 384><<<gemmBlocks, 512, 0, stream>>>(bufA, Wp2, bufB);
  k_al<3><<<nodeWaveBlocks, 256, 0, stream>>>(bufB, a2s, a2d, al_s, al_d, N);
  k_attn_agg<3, bf16><<<nodeWaveBlocks, 256, 0, stream>>>(bufB, ssrc, offs, al_s, al_d, b2, bufA, N);

  // ---- layer 3: bufA[N,384] @ W3 -> bufB[N,128], heads=1, fp32 agg out ----
  k_gemm_d<2, 384, 128><<<gemmBlocks, 512, 0, stream>>>(bufA, Wp3, bufB);
  k_al<1><<<nodeWaveBlocks, 256, 0, stream>>>(bufB, a3s, a3d, al_s, al_d, N);
  float* out3 = (float*)bufA;
  k_attn_agg<1, float><<<nodeWaveBlocks, 256, 0, stream>>>(bufB, ssrc, offs, al_s, al_d, b3, out3, N);

  // ---- global mean pool: segmented, atomic-free ----
  k_pool<<<(G * 64 + 255) / 256, 256, 0, stream>>>(out3, goffs, out, G);
}

// Round 7
// 1398.817 us; speedup vs baseline: 1.1811x; 1.0745x over previous
//
#include <hip/hip_runtime.h>
#include <hip/hip_bf16.h>
#include <math.h>

#define LRELU_SLOPE 0.2f
typedef __hip_bfloat16 bf16;
typedef __hip_bfloat162 bf16x2;

typedef short s8v __attribute__((ext_vector_type(8)));   // 8 bf16 (4 VGPRs)
typedef short s4v __attribute__((ext_vector_type(4)));   // 4 bf16 (2 VGPRs)
typedef float f4v __attribute__((ext_vector_type(4)));   // MFMA acc
typedef int   i4v __attribute__((ext_vector_type(4)));
typedef unsigned int u4v __attribute__((ext_vector_type(4)));

__device__ __forceinline__ float lrelu(float v) { return v > 0.f ? v : LRELU_SLOPE * v; }
__device__ __forceinline__ float b2f(short b) {
  return __uint_as_float(((unsigned)(unsigned short)b) << 16);
}

__device__ __forceinline__ void st2(float* p, float x, float y) {
  *(float2*)p = float2{x, y};
}

// ---- streaming store (sc1 + nt): measured NEUTRAL (R4), kept as harmless ----
__device__ __forceinline__ u4v make_srd(const void* p) {
  u4v r;
  unsigned long long a = (unsigned long long)p;
  r.x = (unsigned)a; r.y = (unsigned)(a >> 32);
  r.z = 0xFFFFFFFFu;          // num_records: disable bounds check
  r.w = 0x00020000u;          // raw dword access
  return r;
}
__device__ __forceinline__ void bstore16_nt(u4v srd, int byteoff, i4v d) {
  asm volatile("buffer_store_dwordx4 %0, %1, %2, 0 offen sc1 nt"
               :: "v"(d), "v"(byteoff), "s"(srd));
}

// ---------------- zero helper (avoid hipMemsetAsync in capture) ----------------

__global__ void k_zero(unsigned int* __restrict__ p, long n) {
  long i = (long)blockIdx.x * blockDim.x + threadIdx.x;
  if (i < n) p[i] = 0u;
}

__global__ void k_zero_out(float* __restrict__ out, int n) {
  int i = blockIdx.x * blockDim.x + threadIdx.x;
  if (i < n) out[i] = 0.f;
}

// ---------------- dtype prep ----------------

__global__ void k_cvt(const float* __restrict__ x, bf16* __restrict__ xb, long n) {
  long i = (long)blockIdx.x * blockDim.x + threadIdx.x;
  if (i < n) xb[i] = __float2bfloat16(x[i]);
}

// W[K][NN] (f32) -> fragment-packed B2 (bf16).
// Fragment f = k32*(NN/16) + ct holds the 16x32 tile (cols ct*16..+16,
// k = k32*32..+32) in MFMA B-operand lane order:
//   B2[f*512 + l*8 + j] = W[k32*32 + (l>>4)*8 + j][ct*16 + (l&15)]
// so a wave's bfrag load is ONE fully-coalesced 1KB global load (lane*8 elems).
__global__ void k_tw2(const float* __restrict__ W, bf16* __restrict__ B2, int K, int NN) {
  int tid = blockIdx.x * blockDim.x + threadIdx.x;   // one thread per 8 elems
  int total = (K * NN) >> 3;
  if (tid >= total) return;
  int f = tid >> 6, l = tid & 63;
  int nfr = NN >> 4;
  int k32 = f / nfr, ct = f - k32 * nfr;
  int col = ct * 16 + (l & 15);
  int krow = k32 * 32 + (l >> 4) * 8;
  s8v v;
#pragma unroll
  for (int j = 0; j < 8; ++j) {
    bf16 b = __float2bfloat16(W[(size_t)(krow + j) * NN + col]);
    v[j] = *(short*)&b;
  }
  *(s8v*)&B2[(size_t)tid * 8] = v;
}

// ---------------- preprocessing: counting-sort edges by dst ----------------

__global__ void k_hist(const int* __restrict__ dst, int* __restrict__ deg, int E, int Et) {
  int e = blockIdx.x * blockDim.x + threadIdx.x;
  if (e >= Et) return;
  int d = (e < E) ? dst[e] : (e - E);   // self-loops appended
  atomicAdd(&deg[d], 1);
}

__global__ void k_hist1(const int* __restrict__ idx, int* __restrict__ deg, int n) {
  int i = blockIdx.x * blockDim.x + threadIdx.x;
  if (i < n) atomicAdd(&deg[idx[i]], 1);
}

__global__ void k_scan1(const int* __restrict__ deg, int* __restrict__ offs,
                        int* __restrict__ bsum, int n) {
  __shared__ int sd[256];
  int t = threadIdx.x;
  int base = blockIdx.x * 1024 + t * 4;
  int v[4]; int tsum = 0;
#pragma unroll
  for (int i = 0; i < 4; ++i) { v[i] = (base + i < n) ? deg[base + i] : 0; tsum += v[i]; }
  sd[t] = tsum;
  __syncthreads();
  for (int off = 1; off < 256; off <<= 1) {
    int x = (t >= off) ? sd[t - off] : 0;
    __syncthreads();
    sd[t] += x;
    __syncthreads();
  }
  int excl = sd[t] - tsum;
#pragma unroll
  for (int i = 0; i < 4; ++i) { if (base + i < n) offs[base + i] = excl; excl += v[i]; }
  if (t == 255) bsum[blockIdx.x] = sd[255];
}

// parallel exclusive scan over block sums (nb <= 256 here)
__global__ void k_scan2(int* bsum, int nb) {
  int t = threadIdx.x;
  if (nb > 256) {
    if (t == 0 && blockIdx.x == 0) {
      int run = 0;
      for (int i = 0; i < nb; ++i) { int x = bsum[i]; bsum[i] = run; run += x; }
    }
    return;
  }
  int v = (t < nb) ? bsum[t] : 0;
  int lane = t & 63, wv = t >> 6;
  int s = v;
#pragma unroll
  for (int off = 1; off < 64; off <<= 1) {
    int u = __shfl_up(s, off, 64);
    if (lane >= off) s += u;
  }
  __shared__ int wsum[4];
  if (lane == 63) wsum[wv] = s;
  __syncthreads();
  int add = 0;
  for (int w = 0; w < wv; ++w) add += wsum[w];
  if (t < nb) bsum[t] = add + s - v;   // exclusive
}

__global__ void k_scan3(int* __restrict__ offs, const int* __restrict__ bsum, int n, int total) {
  int t = threadIdx.x;
  int base = blockIdx.x * 1024 + t * 4;
  int add = bsum[blockIdx.x];
#pragma unroll
  for (int i = 0; i < 4; ++i) if (base + i < n) offs[base + i] += add;
  if (blockIdx.x == 0 && t == 0) offs[n] = total;
}

__global__ void k_scatter(const int* __restrict__ src, const int* __restrict__ dst,
                          const int* __restrict__ offs, int* __restrict__ cur,
                          int* __restrict__ ssrc, int E, int Et) {
  int e = blockIdx.x * blockDim.x + threadIdx.x;
  if (e >= Et) return;
  int s, d;
  if (e < E) { s = src[e]; d = dst[e]; } else { s = d = e - E; }
  int pos = offs[d] + atomicAdd(&cur[d], 1);
  ssrc[pos] = s;
}

// ------- tiled MFMA GEMM: C[M,NN] = A[M,K] @ W[K,NN], BM=256 2-phase -------
// Why BM=256: B-fragment traffic from L2 is ~1KB per 16-col tile per k-step per
// wave; at BM=64 (all prior rounds) that is ~1.8 GB/layer and a register-direct
// GEMM can never be MFMA-bound (needs >=15 M-slices/wave -- impossible acc
// budget). B re-read scales 1/BM: BM=256 -> ~900 MB total (~26us L2). A re-read
// x(NN/128) is L3-served (154 MB < 256 MB L3).
// Why 2-phase + launch_bounds(512,4): stage(t+1) issued FIRST, one syncthreads
// per step; <=128 VGPR -> 4 waves/SIMD -> TWO barrier-independent blocks/CU so
// the per-step vmcnt drain of one block overlaps the other block's compute
// (R2's failure: 1 block/CU, nothing to fill the drain).
// 8 waves = 4 M-groups (64 rows) x 2 N-groups (64 cols); acc[4][4] = 64 VGPR.
// LDS: A-slab 256x32 bf16 = 16 KB, x2 double-buffer. XOR chunk-swizzle on the
// global SOURCE + same XOR on ds_read (linear LDS dest -- rule #21) so the
// stride-64B ds_read_b128 is bank-conflict-free.
// M-tail: grid rounds up to 256 rows; buffers are carved padded, so OOB rows
// read/write owned padding (harmless garbage).

template <int K, int NN>
__global__ __launch_bounds__(512, 4) void k_gemm_t(const bf16* __restrict__ A,
                                                   const bf16* __restrict__ B2,
                                                   bf16* __restrict__ C) {
  constexpr int nk = K / 32;
  constexpr int nfr = NN >> 4;
  __shared__ __align__(16) short sA[2][256 * 32];    // 2 x 16 KB
  int t = threadIdx.x;
  int wv = t >> 6, lane = t & 63;
  int mg = wv >> 1, ng = wv & 1;
  int quad = lane >> 4, l15 = lane & 15;
  size_t bm0 = (size_t)blockIdx.x * 256;
  int ctb = blockIdx.y * 8 + ng * 4;                 // first 16-col tile

  // staging map: thread t covers slab row sr (+128 for shot 1), chunk p.
  // chunk swizzle c = p ^ (row & 3); row&3 == sr&3 for both shots (128%4==0).
  int sr = t >> 2, p = t & 3;
  int c = p ^ (sr & 3);
  const bf16* g0 = A + (bm0 + sr) * (size_t)K + c * 8;
  const bf16* g1 = g0 + (size_t)128 * K;
  const bf16* Bp = B2 + ((size_t)ctb << 9) + lane * 8;

  f4v acc[4][4];
#pragma unroll
  for (int ms = 0; ms < 4; ++ms)
#pragma unroll
    for (int bn = 0; bn < 4; ++bn) acc[ms][bn] = f4v{0, 0, 0, 0};

#define STAGE(step, buf)                                                        \
  do {                                                                          \
    __builtin_amdgcn_global_load_lds(                                           \
        (const __attribute__((address_space(1))) void*)(g0 + (step) * 32),      \
        (__attribute__((address_space(3))) void*)((char*)sA[buf] + wv * 1024),  \
        16, 0, 0);                                                              \
    __builtin_amdgcn_global_load_lds(                                           \
        (const __attribute__((address_space(1))) void*)(g1 + (step) * 32),      \
        (__attribute__((address_space(3))) void*)((char*)sA[buf] + 8192 + wv * 1024), \
        16, 0, 0);                                                              \
  } while (0)

  STAGE(0, 0);
  __syncthreads();                       // vmcnt(0): tile 0 landed

  for (int ik = 0; ik < nk; ++ik) {
    int cur = ik & 1;
    if (ik + 1 < nk) STAGE(ik + 1, cur ^ 1);   // issue next tile FIRST

    const char* sb = (const char*)sA[cur];
    s8v af[4];
#pragma unroll
    for (int ms = 0; ms < 4; ++ms) {
      int row = mg * 64 + ms * 16 + l15;
      int pos = quad ^ (row & 3);
      af[ms] = *(const s8v*)(sb + row * 64 + pos * 16);
    }
    s8v pb[4];
#pragma unroll
    for (int bn = 0; bn < 4; ++bn)
      pb[bn] = *(const s8v*)(Bp + ((size_t)(ik * nfr + bn) << 9));
#pragma unroll
    for (int ms = 0; ms < 4; ++ms)
#pragma unroll
      for (int bn = 0; bn < 4; ++bn)
        acc[ms][bn] = __builtin_amdgcn_mfma_f32_16x16x32_bf16(af[ms], pb[bn], acc[ms][bn], 0, 0, 0);

    __syncthreads();                     // drain stage(t+1) + guard buffer reuse
  }
#undef STAGE

  // C/D layout: col = lane&15, row = quad*4 + reg  [m89/m91 verified]
#pragma unroll
  for (int ms = 0; ms < 4; ++ms)
#pragma unroll
    for (int bn = 0; bn < 4; ++bn) {
      int coln = (ctb + bn) * 16 + l15;
      size_t rbase = bm0 + mg * 64 + ms * 16 + quad * 4;
#pragma unroll
      for (int r = 0; r < 4; ++r)
        C[(rbase + r) * NN + coln] = __float2bfloat16(acc[ms][bn][r]);
    }
}

// ---------------- attention logits: one wave per node, 16 lanes per head ----------------
// al_s/al_d stored PADDED to 4 floats per node (H=3) so the per-edge gather in
// k_attn_agg is a single dwordx4 instead of 3 scalar dword gathers.

template <int H>
__global__ void k_al(const bf16* __restrict__ h, const float* __restrict__ as,
                     const float* __restrict__ ad, float* __restrict__ al_s,
                     float* __restrict__ al_d, int N) {
  constexpr int SP = (H > 1) ? 4 : 1;
  int n = (blockIdx.x * blockDim.x + threadIdx.x) >> 6;
  int lane = threadIdx.x & 63;
  if (n >= N) return;
  int hd = lane >> 4;
  bool active = (hd < H);
  int hdc = active ? hd : 0;
  int f8 = (lane & 15) * 8;
  const bf16* hp = h + (size_t)n * (H * 128) + hdc * 128 + f8;
  s8v hv = *(const s8v*)hp;
  float ss = 0.f, sd = 0.f;
#pragma unroll
  for (int i = 0; i < 8; ++i) {
    float v = b2f(hv[i]);
    ss += v * as[hdc * 128 + f8 + i];
    sd += v * ad[hdc * 128 + f8 + i];
  }
#pragma unroll
  for (int off = 8; off; off >>= 1) {
    ss += __shfl_xor(ss, off, 64);
    sd += __shfl_xor(sd, off, 64);
  }
  if (active && (lane & 15) == 0) {
    al_s[n * SP + hd] = ss;
    al_d[n * SP + hd] = sd;
  }
}

// -------- fused segment-softmax + weighted aggregation: one wave per node --------
// (stable at ~241us/layer across 5 rounds; at the random-gather L2-miss floor.)

template <int CPL> struct HVec;
template <> struct HVec<8> { typedef s8v T; };
template <> struct HVec<4> { typedef s4v T; };

template <int H, typename OT>
__global__ __launch_bounds__(256) void k_attn_agg(const bf16* __restrict__ hbuf,
                           const int* __restrict__ ssrc,
                           const int* __restrict__ offs, const float* __restrict__ al_s,
                           const float* __restrict__ al_d, const float* __restrict__ bias,
                           OT* __restrict__ out, int N) {
  constexpr int SW  = (H > 1) ? 4 : 2;   // stash record (floats)
  constexpr int ROW = H * 128;           // channels per node row
  constexpr int CPL = (H > 1) ? 8 : 4;   // channels per active lane
  constexpr int NL  = ROW / CPL;         // active lanes (48 or 32)
  typedef typename HVec<CPL>::T hvec;

  __shared__ __align__(16) float stash[4][64 * SW];
  int n = (blockIdx.x * blockDim.x + threadIdx.x) >> 6;
  int lane = threadIdx.x & 63;
  if (n >= N) return;
  float* st = stash[threadIdx.x >> 6];
  int start = offs[n], end = offs[n + 1];

  float ald[H];
  if constexpr (H > 1) {
    float4 t = *(const float4*)&al_d[(size_t)n * 4];
    ald[0] = t.x; ald[1] = t.y; ald[2] = t.z;
  } else {
    ald[0] = al_d[n];
  }

  bool act = lane < NL;
  int c0 = act ? lane * CPL : 0;
  int hd_l = c0 >> 7;                    // this lane's head (0 for idle lanes)

  float m[H];
  float den = 0.f;                       // own-head denominator
  float acc[CPL];
#pragma unroll
  for (int hd = 0; hd < H; ++hd) m[hd] = -1e30f;
#pragma unroll
  for (int i = 0; i < CPL; ++i) acc[i] = 0.f;

  for (int cb = start; cb < end; cb += 64) {
    int cl = end - cb; if (cl > 64) cl = 64;
    bool el = lane < cl;
    int mys = el ? ssrc[cb + lane] : 0;
    float ev[H];
    if constexpr (H > 1) {
      float4 av = *(const float4*)&al_s[(size_t)mys * 4];
      ev[0] = av.x; ev[1] = av.y; ev[2] = av.z;
    } else {
      ev[0] = al_s[mys];
    }
#pragma unroll
    for (int hd = 0; hd < H; ++hd)
      ev[hd] = el ? lrelu(ev[hd] + ald[hd]) : -1e30f;

    // chunk max (fused -- no separate max pass over the edges)
    float nm[H];
#pragma unroll
    for (int hd = 0; hd < H; ++hd) {
      float v = ev[hd];
#pragma unroll
      for (int off = 32; off; off >>= 1) v = fmaxf(v, __shfl_xor(v, off, 64));
      nm[hd] = fmaxf(v, m[hd]);
    }
    if (cb > start) {                    // online rescale; wave-uniform branch
      float sc[H];
#pragma unroll
      for (int hd = 0; hd < H; ++hd) sc[hd] = __expf(m[hd] - nm[hd]);
      float so = sc[hd_l];
      den *= so;
#pragma unroll
      for (int i = 0; i < CPL; ++i) acc[i] *= so;
    }
#pragma unroll
    for (int hd = 0; hd < H; ++hd) m[hd] = nm[hd];

    float myex[H];
#pragma unroll
    for (int hd = 0; hd < H; ++hd) myex[hd] = el ? __expf(ev[hd] - m[hd]) : 0.f;

    // stash this chunk's edge records (wave-private region; wave-synchronous)
    __builtin_amdgcn_wave_barrier();
    if constexpr (H > 1) {
      float4 s4{__int_as_float(mys), myex[0], myex[1], myex[2]};
      *(float4*)&st[lane * 4] = s4;
    } else {
      float2 s2{__int_as_float(mys), myex[0]};
      *(float2*)&st[lane * 2] = s2;
    }
    asm volatile("s_waitcnt lgkmcnt(0)" ::: "memory");
    __builtin_amdgcn_wave_barrier();

    for (int r = 0; r < cl; r += 8) {
      int su[8]; float a[8];
#pragma unroll
      for (int u = 0; u < 8; ++u) {
        if constexpr (H > 1) {
          float4 ed = *(const float4*)&st[(r + u) * 4];   // broadcast ds_read_b128
          su[u] = __float_as_int(ed.x);
          a[u] = (hd_l == 0) ? ed.y : ((hd_l == 1) ? ed.z : ed.w);
        } else {
          float2 ed = *(const float2*)&st[(r + u) * 2];
          su[u] = __float_as_int(ed.x);
          a[u] = ed.y;
        }
        den += a[u];                     // tail slots stash a==0
      }
      hvec hv[8];
#pragma unroll
      for (int u = 0; u < 8; ++u)
        hv[u] = *(const hvec*)(hbuf + (size_t)su[u] * ROW + c0);
#pragma unroll
      for (int u = 0; u < 8; ++u)
#pragma unroll
        for (int i = 0; i < CPL; ++i)
          acc[i] += a[u] * b2f(hv[u][i]);
    }
  }

  if (act) {
    float rr = 1.f / (den + 1e-16f);
    u4v srd = make_srd(out);
    int boff = (int)(((size_t)n * ROW + c0) * sizeof(OT));
    if constexpr (sizeof(OT) == 2) {
      union { s8v s; i4v i; } u;
#pragma unroll
      for (int i = 0; i < CPL; ++i) {
        float o = lrelu(acc[i] * rr + bias[c0 + i]);
        bf16 b = __float2bfloat16(o);
        u.s[i] = *(short*)&b;
      }
      bstore16_nt(srd, boff, u.i);
    } else {
      union { float4 f; i4v i; } u;
      u.f.x = lrelu(acc[0] * rr + bias[c0 + 0]);
      u.f.y = lrelu(acc[1] * rr + bias[c0 + 1]);
      u.f.z = lrelu(acc[2] * rr + bias[c0 + 2]);
      u.f.w = lrelu(acc[3] * rr + bias[c0 + 3]);
      bstore16_nt(srd, boff, u.i);
    }
  }
}

// ---------------- global mean pool: one wave per graph, no atomics ----------------

__global__ void k_pool(const float* __restrict__ h, const int* __restrict__ goffs,
                       float* __restrict__ out, int G) {
  int g = (blockIdx.x * blockDim.x + threadIdx.x) >> 6;
  int lane = threadIdx.x & 63;
  if (g >= G) return;
  int s = goffs[g], e = goffs[g + 1];
  float ax = 0.f, ay = 0.f;
  for (int n = s; n < e; ++n) {
    float2 v = *(const float2*)&h[(size_t)n * 128 + lane * 2];
    ax += v.x; ay += v.y;
  }
  float c = fmaxf((float)(e - s), 1.f);
  st2(&out[(size_t)g * 128 + lane * 2], ax / c, ay / c);
}

// ---------------- host launcher ----------------

extern "C" void kernel_launch(void* const* d_in, const int* in_sizes, int n_in,
                              void* d_out, int out_size, void* d_ws, size_t ws_size,
                              hipStream_t stream) {
  const float* x   = (const float*)d_in[0];
  const int*   ei  = (const int*)d_in[1];
  const int*   bat = (const int*)d_in[2];
  const float* W1  = (const float*)d_in[3];
  const float* a1s = (const float*)d_in[4];
  const float* a1d = (const float*)d_in[5];
  const float* b1  = (const float*)d_in[6];
  const float* W2  = (const float*)d_in[7];
  const float* a2s = (const float*)d_in[8];
  const float* a2d = (const float*)d_in[9];
  const float* b2  = (const float*)d_in[10];
  const float* W3  = (const float*)d_in[11];
  const float* a3s = (const float*)d_in[12];
  const float* a3d = (const float*)d_in[13];
  const float* b3  = (const float*)d_in[14];
  float* out = (float*)d_out;

  const int N = in_sizes[2];          // 200000
  const int E = in_sizes[1] / 2;      // 1600000
  const int Et = E + N;               // with self-loops
  const int G = out_size / 128;       // 5000

  const int MB = (N + 255) / 256;     // 256-row GEMM blocks
  const int Mpad = MB * 256;          // padded rows (tail rows are owned garbage)

  // ---- workspace carve (bf16 intermediates; buffers padded to Mpad rows) ----
  char* p = (char*)d_ws;
  auto carve = [&](size_t bytes) { void* r = (void*)p; p += (bytes + 255) & ~(size_t)255; return r; };
  bf16*  bufA   = (bf16*)carve((size_t)Mpad * 384 * 2);  // agg out / GEMM A; also hosts xb & fp32 layer-3 out
  bf16*  bufB   = (bf16*)carve((size_t)Mpad * 384 * 2);  // GEMM output h
  float* al_s   = (float*)carve((size_t)N * 4 * 4);      // padded to 4 floats/node
  float* al_d   = (float*)carve((size_t)N * 4 * 4);
  int*   ssrc   = (int*)carve((size_t)Et * 4);
  int*   offs   = (int*)carve((size_t)(N + 1) * 4);
  int*   deg    = (int*)carve((size_t)N * 4);
  int*   cur    = (int*)carve((size_t)N * 4);
  int*   bsum   = (int*)carve(4096 * 4);
  int*   gdeg   = (int*)carve((size_t)G * 4);
  int*   goffs  = (int*)carve((size_t)(G + 1) * 4);
  bf16*  Wp1    = (bf16*)carve((size_t)384 * 128 * 2);   // packed B2 buffers
  bf16*  Wp2    = (bf16*)carve((size_t)384 * 384 * 2);
  bf16*  Wp3    = (bf16*)carve((size_t)128 * 384 * 2);
  size_t need = (size_t)(p - (char*)d_ws);

  if (ws_size < need) {
    k_zero_out<<<(out_size + 255) / 256, 256, 0, stream>>>(out, out_size);
    return;
  }

  const int* esrc = ei;
  const int* edst = ei + E;

  int ebl = (Et + 255) / 256;
  int NB = (N + 1023) / 1024;
  int GB = (G + 1023) / 1024;
  int nodeWaveBlocks = (N * 64 + 255) / 256;

  // ---- prep: weight pack+cast, x cast (xb aliases bufA) ----
  bf16* xb = bufA;
  k_cvt<<<((long)N * 128 + 255) / 256, 256, 0, stream>>>(x, xb, (long)N * 128);
  k_tw2<<<(128 * 384 / 8 + 255) / 256, 256, 0, stream>>>(W1, Wp1, 128, 384);
  k_tw2<<<(384 * 384 / 8 + 255) / 256, 256, 0, stream>>>(W2, Wp2, 384, 384);
  k_tw2<<<(384 * 128 / 8 + 255) / 256, 256, 0, stream>>>(W3, Wp3, 384, 128);

  // ---- sort edges by dst ----
  k_zero<<<(N + 255) / 256, 256, 0, stream>>>((unsigned int*)deg, N);
  k_hist<<<ebl, 256, 0, stream>>>(edst, deg, E, Et);
  k_scan1<<<NB, 256, 0, stream>>>(deg, offs, bsum, N);
  k_scan2<<<1, 256, 0, stream>>>(bsum, NB);
  k_scan3<<<NB, 256, 0, stream>>>(offs, bsum, N, Et);
  k_zero<<<(N + 255) / 256, 256, 0, stream>>>((unsigned int*)cur, N);
  k_scatter<<<ebl, 256, 0, stream>>>(esrc, edst, offs, cur, ssrc, E, Et);

  // ---- graph offsets for pool (batch is sorted) ----
  k_zero<<<(G + 255) / 256, 256, 0, stream>>>((unsigned int*)gdeg, G);
  k_hist1<<<(N + 255) / 256, 256, 0, stream>>>(bat, gdeg, N);
  k_scan1<<<GB, 256, 0, stream>>>(gdeg, goffs, bsum, G);
  k_scan2<<<1, 256, 0, stream>>>(bsum, GB);
  k_scan3<<<GB, 256, 0, stream>>>(goffs, bsum, G, N);

  // ---- layer 1: xb[N,128] @ W1 -> bufB[N,384] ----
  k_gemm_t<128, 384><<<dim3(MB, 3), 512, 0, stream>>>(xb, Wp1, bufB);
  k_al<3><<<nodeWaveBlocks, 256, 0, stream>>>(bufB, a1s, a1d, al_s, al_d, N);
  k_attn_agg<3, bf16><<<nodeWaveBlocks, 256, 0, stream>>>(bufB, ssrc, offs, al_s, al_d, b1, bufA, N);

  // ---- layer 2: bufA[N,384] @ W2 -> bufB[N,384] ----
  k_gemm_t<384, 384><<<dim3(MB, 3), 512, 0, stream>>>(bufA, Wp2, bufB);
  k_al<3><<<nodeWaveBlocks, 256, 0, stream>>>(bufB, a2s, a2d, al_s, al_d, N);
  k_attn_agg<3, bf16><<<nodeWaveBlocks, 256, 0, stream>>>(bufB, ssrc, offs, al_s, al_d, b2, bufA, N);

  // ---- layer 3: bufA[N,384] @ W3 -> bufB[N,128], heads=1, fp32 agg out ----
  k_gemm_t<384, 128><<<dim3(MB, 1), 512, 0, stream>>>(bufA, Wp3, bufB);
  k_al<1><<<nodeWaveBlocks, 256, 0, stream>>>(bufB, a3s, a3d, al_s, al_d, N);
  float* out3 = (float*)bufA;
  k_attn_agg<1, float><<<nodeWaveBlocks, 256, 0, stream>>>(bufB, ssrc, offs, al_s, al_d, b3, out3, N);

  // ---- global mean pool: segmented, atomic-free ----
  k_pool<<<(G * 64 + 255) / 256, 256, 0, stream>>>(out3, goffs, out, G);
}